// Round 6
// baseline (1508.763 us; speedup 1.0000x reference)
//
#include <hip/hip_runtime.h>
#include <math.h>

#define NN 3136      // H*W = 56*56
#define CC 96
#define BB 8
#define KNB 9
#define PARTS 7      // m-range split: 7 parts x 7 mt x 64 = 3136 cols
#define FLT_MAX_ 3.402823466e+38f
typedef unsigned long long u64;

// ---------------------------------------------------------------------------
// 1x1 conv as batched GEMM (baseline version, known-good)
// ---------------------------------------------------------------------------
__global__ __launch_bounds__(256) void conv1_kernel(
    const float* __restrict__ in, const float* __restrict__ w,
    const float* __restrict__ bias, float* __restrict__ out, int K, int O)
{
    __shared__ float sW[16][64];   // [kk][o]
    __shared__ float sX[16][64];   // [kk][n]
    const int b  = blockIdx.z;
    const int n0 = blockIdx.x * 64;
    const int o0 = blockIdx.y * 64;
    const int tid = threadIdx.x;
    const int tx = tid & 15, ty = tid >> 4;
    const float* inb = in + (size_t)b * K * NN;

    float acc[4][4] = {{0.f}};

    for (int kb = 0; kb < K; kb += 16) {
        __syncthreads();
        {
            int o  = tid >> 2;
            int k4 = (tid & 3) << 2;
            float4 wv = make_float4(0.f, 0.f, 0.f, 0.f);
            if (o0 + o < O)
                wv = *(const float4*)&w[(size_t)(o0 + o) * K + kb + k4];
            sW[k4 + 0][o] = wv.x; sW[k4 + 1][o] = wv.y;
            sW[k4 + 2][o] = wv.z; sW[k4 + 3][o] = wv.w;
        }
        #pragma unroll
        for (int i = 0; i < 4; i++) {
            int e = tid + i * 256;
            int kk = e >> 6, n2 = e & 63;
            sX[kk][n2] = inb[(size_t)(kb + kk) * NN + n0 + n2];
        }
        __syncthreads();
        #pragma unroll
        for (int kk = 0; kk < 16; kk++) {
            const float4 av = *(const float4*)&sW[kk][ty << 2];
            const float4 xv = *(const float4*)&sX[kk][tx << 2];
            float a_[4] = {av.x, av.y, av.z, av.w};
            float x_[4] = {xv.x, xv.y, xv.z, xv.w};
            #pragma unroll
            for (int i = 0; i < 4; i++)
                #pragma unroll
                for (int j = 0; j < 4; j++)
                    acc[i][j] = fmaf(a_[i], x_[j], acc[i][j]);
        }
    }
    #pragma unroll
    for (int i = 0; i < 4; i++) {
        int o = o0 + (ty << 2) + i;
        if (o < O) {
            float bo = bias[o];
            float4 v = make_float4(acc[i][0] + bo, acc[i][1] + bo,
                                   acc[i][2] + bo, acc[i][3] + bo);
            *(float4*)&out[((size_t)b * O + o) * NN + n0 + (tx << 2)] = v;
        }
    }
}

// ---------------------------------------------------------------------------
// Instance norm over N per (b,c) row; act: 0 none, 1 gelu, 2 relu
// ---------------------------------------------------------------------------
__global__ __launch_bounds__(256) void inorm_kernel(
    const float* __restrict__ in, float* __restrict__ out,
    const float* __restrict__ res, int act)
{
    const int row = blockIdx.x;
    const float* x = in + (size_t)row * NN;
    const int tid = threadIdx.x;

    float v[13];
    float s = 0.f;
    #pragma unroll
    for (int i = 0; i < 13; i++) {
        int idx = tid + i * 256;
        v[i] = (idx < NN) ? x[idx] : 0.f;
        s += v[i];
    }
    __shared__ float red[4];
    #pragma unroll
    for (int off = 32; off > 0; off >>= 1) s += __shfl_down(s, off);
    if ((tid & 63) == 0) red[tid >> 6] = s;
    __syncthreads();
    const float mean = (red[0] + red[1] + red[2] + red[3]) * (1.f / (float)NN);

    float s2 = 0.f;
    #pragma unroll
    for (int i = 0; i < 13; i++) {
        int idx = tid + i * 256;
        if (idx < NN) { float d = v[i] - mean; s2 = fmaf(d, d, s2); }
    }
    #pragma unroll
    for (int off = 32; off > 0; off >>= 1) s2 += __shfl_down(s2, off);
    __syncthreads();
    if ((tid & 63) == 0) red[tid >> 6] = s2;
    __syncthreads();
    const float var = (red[0] + red[1] + red[2] + red[3]) * (1.f / (float)NN);
    const float rs = rsqrtf(var + 1e-5f);

    float* o = out + (size_t)row * NN;
    const float* rr = res ? (res + (size_t)row * NN) : nullptr;
    #pragma unroll
    for (int i = 0; i < 13; i++) {
        int idx = tid + i * 256;
        if (idx < NN) {
            float y = (v[i] - mean) * rs;
            if (act == 1)      y = 0.5f * y * (1.f + erff(y * 0.70710678118654752f));
            else if (act == 2) y = fmaxf(y, 0.f);
            if (rr) y += rr[idx];
            o[idx] = y;
        }
    }
}

// ---------------------------------------------------------------------------
// Column (channel) L2-normalize + sq[b,n] = sum_c xn^2
// ---------------------------------------------------------------------------
__global__ __launch_bounds__(256) void colnorm_kernel(
    const float* __restrict__ xf, float* __restrict__ xn,
    float* __restrict__ sqc)
{
    const int g = blockIdx.x * 256 + threadIdx.x;   // over B*N
    const int b = g / NN;
    const int n = g - b * NN;
    const float* p = xf + (size_t)b * CC * NN + n;
    float* q = xn + (size_t)b * CC * NN + n;

    float s = 0.f;
    for (int c = 0; c < CC; c++) { float t = p[(size_t)c * NN]; s = fmaf(t, t, s); }
    const float den = fmaxf(sqrtf(s), 1e-12f);

    float sq = 0.f;
    for (int c = 0; c < CC; c++) {
        float t = p[(size_t)c * NN] / den;
        q[(size_t)c * NN] = t;
        sq = fmaf(t, t, sq);
    }
    sqc[g] = sq;
}

// ---------------------------------------------------------------------------
// u64-key top-9: key = (ord(dist) << 32) | m.  min-u64 == (min d, then min m)
// == reference top_k tie-break (stable, lower index first).
// ---------------------------------------------------------------------------
__device__ __forceinline__ u64 dkey(float d, int m)
{
    unsigned int ub = __float_as_uint(d);
    ub ^= (unsigned int)(((int)ub) >> 31) | 0x80000000u;
    return ((u64)ub << 32) | (unsigned int)m;
}
__device__ __forceinline__ void ins9u(u64 (&kk)[9], u64 key)
{
    if (key < kk[8]) {
        kk[8] = key;
        #pragma unroll
        for (int j = 8; j > 0; --j) {
            if (kk[j] < kk[j - 1]) {
                u64 t = kk[j]; kk[j] = kk[j - 1]; kk[j - 1] = t;
            }
        }
    }
}

// ---------------------------------------------------------------------------
// Fused distance GEMM + top-9 select (v3).
// 4x4 micro-tile: tx (0..15) -> 4 cols, ty (0..15) -> 4 rows.
// Per c-iter: 2x ds_read_b128 (24 cyc LDS) vs 16 FMA (32 cyc VALU) -- the
// FMA loop is VALU-bound, no longer LDS-gated (v2 was at parity).
// shC staging is register-prefetched: global loads for mt+1 issued before
// the mt FMA loop, ds_writes after the next barrier -> L2 latency hidden.
// Out: 9 sorted u64 keys per (row, part) -> pko.
// grid: (NN/64, PARTS, BB), 256 threads.
// ---------------------------------------------------------------------------
__global__ __launch_bounds__(256) void knn_fused_kernel(
    const float* __restrict__ xn, const float* __restrict__ sqc,
    const float* __restrict__ rp, u64* __restrict__ pko)
{
    __shared__ float shR[CC * 64];    // [c][r]   24 KB, persistent
    __shared__ float shC[CC * 64];    // [c][m]   24 KB, restaged per m-tile
    const int b    = blockIdx.z;
    const int part = blockIdx.y;
    const int r0   = blockIdx.x * 64;
    const int tid  = threadIdx.x;
    const int tx = tid & 15;          // 16 col groups of 4
    const int ty = tid >> 4;          // 16 row groups of 4
    const float* xb  = xn  + (size_t)b * CC * NN;
    const float* sqb = sqc + (size_t)b * NN;

    // stage 64-row slab of xn (float4, coalesced); visible after 1st barrier
    #pragma unroll
    for (int i = 0; i < 6; i++) {
        int idx = tid + i * 256;              // 1536 float4s
        int c = idx >> 4, r4 = (idx & 15) << 2;
        *(float4*)&shR[c * 64 + r4] = *(const float4*)&xb[(size_t)c * NN + r0 + r4];
    }

    u64 kk[4][9];
    #pragma unroll
    for (int i = 0; i < 4; i++)
        #pragma unroll
        for (int j = 0; j < 9; j++) kk[i][j] = 0xFFFFFFFFFFFFFFFFull;

    const int rA = r0 + ty * 4;           // first of this thread's 4 rows

    // prefetch shC data for mt=0 into registers
    float4 nx[6];
    {
        const int m0 = part * PARTS * 64;
        #pragma unroll
        for (int i = 0; i < 6; i++) {
            int idx = tid + i * 256;
            int c = idx >> 4, m4 = (idx & 15) << 2;
            nx[i] = *(const float4*)&xb[(size_t)c * NN + m0 + m4];
        }
    }

    for (int mt = 0; mt < PARTS; mt++) {
        const int m0 = (part * PARTS + mt) * 64;

        __syncthreads();   // (A) all reads of shC for mt-1 complete
        #pragma unroll
        for (int i = 0; i < 6; i++) {
            int idx = tid + i * 256;
            int c = idx >> 4, m4 = (idx & 15) << 2;
            *(float4*)&shC[c * 64 + m4] = nx[i];
        }
        // issue next-tile global loads now; latency hides under FMA loop
        if (mt + 1 < PARTS) {
            const int m0n = m0 + 64;
            #pragma unroll
            for (int i = 0; i < 6; i++) {
                int idx = tid + i * 256;
                int c = idx >> 4, m4 = (idx & 15) << 2;
                nx[i] = *(const float4*)&xb[(size_t)c * NN + m0n + m4];
            }
        }
        // rp/sq for this mt: issued here, consumed in epilogue
        const float4 sqv = *(const float4*)&sqb[m0 + tx * 4];
        const float4 rp0 = *(const float4*)&rp[(size_t)(rA + 0) * NN + m0 + tx * 4];
        const float4 rp1 = *(const float4*)&rp[(size_t)(rA + 1) * NN + m0 + tx * 4];
        const float4 rp2 = *(const float4*)&rp[(size_t)(rA + 2) * NN + m0 + tx * 4];
        const float4 rp3 = *(const float4*)&rp[(size_t)(rA + 3) * NN + m0 + tx * 4];
        __syncthreads();   // (B) shC staged

        float acc[4][4] = {{0.f}};
        #pragma unroll 4
        for (int c = 0; c < CC; c++) {
            const float4 rv = *(const float4*)&shR[c * 64 + ty * 4];
            const float4 cv = *(const float4*)&shC[c * 64 + tx * 4];
            const float r_[4] = {rv.x, rv.y, rv.z, rv.w};
            const float c_[4] = {cv.x, cv.y, cv.z, cv.w};
            #pragma unroll
            for (int i = 0; i < 4; i++)
                #pragma unroll
                for (int j = 0; j < 4; j++)
                    acc[i][j] = fmaf(r_[i], c_[j], acc[i][j]);
        }

        // epilogue: distances -> u64 keys -> per-thread top-9 per row
        const float sq_[4] = {sqv.x, sqv.y, sqv.z, sqv.w};
        const float rpv[4][4] = {{rp0.x, rp0.y, rp0.z, rp0.w},
                                 {rp1.x, rp1.y, rp1.z, rp1.w},
                                 {rp2.x, rp2.y, rp2.z, rp2.w},
                                 {rp3.x, rp3.y, rp3.z, rp3.w}};
        #pragma unroll
        for (int i = 0; i < 4; i++)
            #pragma unroll
            for (int j = 0; j < 4; j++) {
                const int m = m0 + tx * 4 + j;
                ins9u(kk[i], dkey(fmaf(-2.f, acc[i][j], sq_[j] + rpv[i][j]), m));
            }
    }

    // tournament merge across the aligned 16-lane col-group per row:
    // 9 rounds of butterfly-min over lane heads, pop unique winner.
    #pragma unroll
    for (int i = 0; i < 4; i++) {
        const size_t base = ((size_t)(b * NN + rA + i) * PARTS + part) * KNB;
        #pragma unroll
        for (int k = 0; k < 9; k++) {
            u64 w = kk[i][0];
            #pragma unroll
            for (int off = 1; off < 16; off <<= 1) {
                unsigned int lo = __shfl_xor((unsigned int)w, off);
                unsigned int hi = __shfl_xor((unsigned int)(w >> 32), off);
                u64 o = ((u64)hi << 32) | lo;
                w = (o < w) ? o : w;
            }
            if (kk[i][0] == w) {          // unique winner (keys contain m)
                #pragma unroll
                for (int j = 0; j < 8; j++) kk[i][j] = kk[i][j + 1];
                kk[i][8] = 0xFFFFFFFFFFFFFFFFull;
            }
            if (tx == 0) pko[base + k] = w;
        }
    }
}

// ---------------------------------------------------------------------------
// Merge PARTS sorted 9-lists (u64 keys) per (b,n) -> final nn_idx
// ---------------------------------------------------------------------------
__global__ __launch_bounds__(256) void knn_merge_kernel(
    const u64* __restrict__ pko, int* __restrict__ nn_idx)
{
    const int g = blockIdx.x * 256 + threadIdx.x;   // over B*N
    if (g >= BB * NN) return;
    u64 kk[9];
    #pragma unroll
    for (int j = 0; j < 9; j++) kk[j] = 0xFFFFFFFFFFFFFFFFull;
    const u64* v = pko + (size_t)g * PARTS * KNB;
    for (int p = 0; p < PARTS; p++)
        #pragma unroll
        for (int j = 0; j < 9; j++)
            ins9u(kk, v[p * KNB + j]);
    #pragma unroll
    for (int j = 0; j < 9; j++)
        nn_idx[(size_t)g * KNB + j] = (int)(kk[j] & 0xFFFFFFFFu);
}

// ---------------------------------------------------------------------------
// Max-relative gather + channel interleave
// ---------------------------------------------------------------------------
__global__ __launch_bounds__(256) void gather_kernel(
    const float* __restrict__ xf, const int* __restrict__ nn_idx,
    float* __restrict__ y)
{
    const size_t g = (size_t)blockIdx.x * 256 + threadIdx.x;   // over B*C*N
    const int n  = (int)(g % NN);
    const int bc = (int)(g / NN);
    const int c  = bc % CC;
    const int b  = bc / CC;
    const float* row = xf + (size_t)(b * CC + c) * NN;
    const float xi = row[n];
    const int* id = nn_idx + ((size_t)b * NN + n) * KNB;
    float mx = -FLT_MAX_;
    #pragma unroll
    for (int k = 0; k < KNB; k++) mx = fmaxf(mx, row[id[k]] - xi);
    float* o = y + ((size_t)b * 2 * CC + 2 * c) * NN + n;
    o[0]  = xi;
    o[NN] = mx;
}

// ---------------------------------------------------------------------------
// Host-side orchestration
// ---------------------------------------------------------------------------
static void conv1(const float* in, const float* w, const float* b, float* out,
                  int K, int O, hipStream_t s)
{
    dim3 grid(NN / 64, (O + 63) / 64, BB);
    conv1_kernel<<<grid, 256, 0, s>>>(in, w, b, out, K, O);
}
static void inorm(const float* in, float* out, const float* res, int ch, int act,
                  hipStream_t s)
{
    inorm_kernel<<<BB * ch, 256, 0, s>>>(in, out, res, act);
}

struct GrapherP {
    const float *fc1w, *fc1b, *mrw, *mrb, *fc2w, *fc2b;
};

static void run_grapher(const float* in, const float* rp, const GrapherP& p,
                        float* outCur, float* bufA, float* bufB, float* xnb,
                        float* sqc, int* idx, hipStream_t s)
{
    conv1(in, p.fc1w, p.fc1b, bufA, CC, CC, s);
    inorm(bufA, bufB, nullptr, CC, 0, s);                         // xf
    colnorm_kernel<<<(BB * NN) / 256, 256, 0, s>>>(bufB, xnb, sqc);
    // partial-key scratch lives in bufA (free until gather writes it):
    // B*N*PARTS*9 u64 = 12.6 MB << P4 floats
    u64* pko = (u64*)bufA;
    knn_fused_kernel<<<dim3(NN / 64, PARTS, BB), 256, 0, s>>>(xnb, sqc, rp, pko);
    knn_merge_kernel<<<(BB * NN + 255) / 256, 256, 0, s>>>(pko, idx);
    gather_kernel<<<(BB * CC * NN) / 256, 256, 0, s>>>(bufB, idx, bufA);  // 2C
    conv1(bufA, p.mrw, p.mrb, bufB, 2 * CC, 2 * CC, s);
    inorm(bufB, bufA, nullptr, 2 * CC, 1, s);                     // gelu
    conv1(bufA, p.fc2w, p.fc2b, bufB, 2 * CC, CC, s);
    inorm(bufB, outCur, in, CC, 0, s);                            // + shortcut
}

static void run_ffn(const float* in, const float* w1, const float* b1,
                    const float* w2, const float* b2,
                    float* outCur, float* bufA, float* bufB, hipStream_t s)
{
    conv1(in, w1, b1, bufA, CC, 4 * CC, s);
    inorm(bufA, bufB, nullptr, 4 * CC, 1, s);                     // gelu
    conv1(bufB, w2, b2, bufA, 2 * CC * 2, CC, s);
    inorm(bufA, outCur, in, CC, 0, s);                            // + shortcut
}

extern "C" void kernel_launch(void* const* d_in, const int* in_sizes, int n_in,
                              void* d_out, int out_size, void* d_ws, size_t ws_size,
                              hipStream_t stream)
{
    const float* x  = (const float*)d_in[0];
    const float* rp = (const float*)d_in[1];
    GrapherP g1 = {(const float*)d_in[2],  (const float*)d_in[3],
                   (const float*)d_in[4],  (const float*)d_in[5],
                   (const float*)d_in[6],  (const float*)d_in[7]};
    GrapherP g2 = {(const float*)d_in[8],  (const float*)d_in[9],
                   (const float*)d_in[10], (const float*)d_in[11],
                   (const float*)d_in[12], (const float*)d_in[13]};
    const float* f1w1 = (const float*)d_in[14]; const float* f1b1 = (const float*)d_in[15];
    const float* f1w2 = (const float*)d_in[16]; const float* f1b2 = (const float*)d_in[17];
    const float* f2w1 = (const float*)d_in[18]; const float* f2b1 = (const float*)d_in[19];
    const float* f2w2 = (const float*)d_in[20]; const float* f2b2 = (const float*)d_in[21];
    float* out = (float*)d_out;

    const size_t P  = (size_t)BB * CC * NN;     // 2,408,448 floats
    const size_t P4 = 4 * P;
    float* ws   = (float*)d_ws;
    float* bufA = ws;                 // P4
    float* bufB = bufA + P4;          // P4
    float* xnb  = bufB + P4;          // P
    float* cur0 = xnb + P;            // P
    float* cur1 = cur0 + P;           // P
    float* sqc  = cur1 + P;           // B*N
    int*   idx  = (int*)(sqc + (size_t)BB * NN);   // B*N*9 ints

    run_grapher(x, rp, g1, cur0, bufA, bufB, xnb, sqc, idx, stream);
    run_ffn(cur0, f1w1, f1b1, f1w2, f1b2, cur1, bufA, bufB, stream);
    inorm(cur1, cur0, nullptr, CC, 2, stream);
    run_grapher(cur0, rp, g2, cur1, bufA, bufB, xnb, sqc, idx, stream);
    run_ffn(cur1, f2w1, f2b1, f2w2, f2b2, cur0, bufA, bufB, stream);
    inorm(cur0, out, x, CC, 0, stream);
    (void)in_sizes; (void)n_in; (void)out_size; (void)ws_size;
}

// Round 7
// 1483.362 us; speedup vs baseline: 1.0171x; 1.0171x over previous
//
#include <hip/hip_runtime.h>
#include <math.h>

#define NN 3136      // H*W = 56*56
#define CC 96
#define BB 8
#define KNB 9
#define PARTS 7      // m-range split: 7 parts x 7 mt x 64 = 3136 cols
#define FLT_MAX_ 3.402823466e+38f
typedef unsigned long long u64;

// ---------------------------------------------------------------------------
// 1x1 conv as batched GEMM (baseline version, known-good)
// ---------------------------------------------------------------------------
__global__ __launch_bounds__(256) void conv1_kernel(
    const float* __restrict__ in, const float* __restrict__ w,
    const float* __restrict__ bias, float* __restrict__ out, int K, int O)
{
    __shared__ float sW[16][64];   // [kk][o]
    __shared__ float sX[16][64];   // [kk][n]
    const int b  = blockIdx.z;
    const int n0 = blockIdx.x * 64;
    const int o0 = blockIdx.y * 64;
    const int tid = threadIdx.x;
    const int tx = tid & 15, ty = tid >> 4;
    const float* inb = in + (size_t)b * K * NN;

    float acc[4][4] = {{0.f}};

    for (int kb = 0; kb < K; kb += 16) {
        __syncthreads();
        {
            int o  = tid >> 2;
            int k4 = (tid & 3) << 2;
            float4 wv = make_float4(0.f, 0.f, 0.f, 0.f);
            if (o0 + o < O)
                wv = *(const float4*)&w[(size_t)(o0 + o) * K + kb + k4];
            sW[k4 + 0][o] = wv.x; sW[k4 + 1][o] = wv.y;
            sW[k4 + 2][o] = wv.z; sW[k4 + 3][o] = wv.w;
        }
        #pragma unroll
        for (int i = 0; i < 4; i++) {
            int e = tid + i * 256;
            int kk = e >> 6, n2 = e & 63;
            sX[kk][n2] = inb[(size_t)(kb + kk) * NN + n0 + n2];
        }
        __syncthreads();
        #pragma unroll
        for (int kk = 0; kk < 16; kk++) {
            const float4 av = *(const float4*)&sW[kk][ty << 2];
            const float4 xv = *(const float4*)&sX[kk][tx << 2];
            float a_[4] = {av.x, av.y, av.z, av.w};
            float x_[4] = {xv.x, xv.y, xv.z, xv.w};
            #pragma unroll
            for (int i = 0; i < 4; i++)
                #pragma unroll
                for (int j = 0; j < 4; j++)
                    acc[i][j] = fmaf(a_[i], x_[j], acc[i][j]);
        }
    }
    #pragma unroll
    for (int i = 0; i < 4; i++) {
        int o = o0 + (ty << 2) + i;
        if (o < O) {
            float bo = bias[o];
            float4 v = make_float4(acc[i][0] + bo, acc[i][1] + bo,
                                   acc[i][2] + bo, acc[i][3] + bo);
            *(float4*)&out[((size_t)b * O + o) * NN + n0 + (tx << 2)] = v;
        }
    }
}

// ---------------------------------------------------------------------------
// Instance norm over N per (b,c) row; act: 0 none, 1 gelu, 2 relu
// ---------------------------------------------------------------------------
__global__ __launch_bounds__(256) void inorm_kernel(
    const float* __restrict__ in, float* __restrict__ out,
    const float* __restrict__ res, int act)
{
    const int row = blockIdx.x;
    const float* x = in + (size_t)row * NN;
    const int tid = threadIdx.x;

    float v[13];
    float s = 0.f;
    #pragma unroll
    for (int i = 0; i < 13; i++) {
        int idx = tid + i * 256;
        v[i] = (idx < NN) ? x[idx] : 0.f;
        s += v[i];
    }
    __shared__ float red[4];
    #pragma unroll
    for (int off = 32; off > 0; off >>= 1) s += __shfl_down(s, off);
    if ((tid & 63) == 0) red[tid >> 6] = s;
    __syncthreads();
    const float mean = (red[0] + red[1] + red[2] + red[3]) * (1.f / (float)NN);

    float s2 = 0.f;
    #pragma unroll
    for (int i = 0; i < 13; i++) {
        int idx = tid + i * 256;
        if (idx < NN) { float d = v[i] - mean; s2 = fmaf(d, d, s2); }
    }
    #pragma unroll
    for (int off = 32; off > 0; off >>= 1) s2 += __shfl_down(s2, off);
    __syncthreads();
    if ((tid & 63) == 0) red[tid >> 6] = s2;
    __syncthreads();
    const float var = (red[0] + red[1] + red[2] + red[3]) * (1.f / (float)NN);
    const float rs = rsqrtf(var + 1e-5f);

    float* o = out + (size_t)row * NN;
    const float* rr = res ? (res + (size_t)row * NN) : nullptr;
    #pragma unroll
    for (int i = 0; i < 13; i++) {
        int idx = tid + i * 256;
        if (idx < NN) {
            float y = (v[i] - mean) * rs;
            if (act == 1)      y = 0.5f * y * (1.f + erff(y * 0.70710678118654752f));
            else if (act == 2) y = fmaxf(y, 0.f);
            if (rr) y += rr[idx];
            o[idx] = y;
        }
    }
}

// ---------------------------------------------------------------------------
// Column (channel) L2-normalize + sq[b,n] = sum_c xn^2
// ---------------------------------------------------------------------------
__global__ __launch_bounds__(256) void colnorm_kernel(
    const float* __restrict__ xf, float* __restrict__ xn,
    float* __restrict__ sqc)
{
    const int g = blockIdx.x * 256 + threadIdx.x;   // over B*N
    const int b = g / NN;
    const int n = g - b * NN;
    const float* p = xf + (size_t)b * CC * NN + n;
    float* q = xn + (size_t)b * CC * NN + n;

    float s = 0.f;
    for (int c = 0; c < CC; c++) { float t = p[(size_t)c * NN]; s = fmaf(t, t, s); }
    const float den = fmaxf(sqrtf(s), 1e-12f);

    float sq = 0.f;
    for (int c = 0; c < CC; c++) {
        float t = p[(size_t)c * NN] / den;
        q[(size_t)c * NN] = t;
        sq = fmaf(t, t, sq);
    }
    sqc[g] = sq;
}

// ---------------------------------------------------------------------------
// u64-key top-9: key = (ord(dist) << 32) | m.  min-u64 == (min d, then min m)
// == reference top_k tie-break (stable, lower index first).
// ---------------------------------------------------------------------------
__device__ __forceinline__ u64 dkey(float d, int m)
{
    unsigned int ub = __float_as_uint(d);
    ub ^= (unsigned int)(((int)ub) >> 31) | 0x80000000u;
    return ((u64)ub << 32) | (unsigned int)m;
}
__device__ __forceinline__ void ins9u(u64 (&kk)[9], u64 key)
{
    if (key < kk[8]) {
        kk[8] = key;
        #pragma unroll
        for (int j = 8; j > 0; --j) {
            if (kk[j] < kk[j - 1]) {
                u64 t = kk[j]; kk[j] = kk[j - 1]; kk[j - 1] = t;
            }
        }
    }
}

// ---------------------------------------------------------------------------
// Fused distance GEMM + top-9 select (v3b = v3 + launch_bounds(256,3)).
// v3 at default launch bounds spilled kk[4][9] to scratch (VGPR capped 80,
// WRITE_SIZE 407 MB). Occupancy is LDS-bound at 3 blocks/CU = 3 waves/EU,
// so min-waves=3 raises the VGPR cap to ~170 (live state ~150) at zero
// occupancy cost.
// 4x4 micro-tile: tx (0..15) -> 4 cols, ty (0..15) -> 4 rows.
// shC staging register-prefetched; rp/sq issued pre-barrier.
// grid: (NN/64, PARTS, BB), 256 threads.
// ---------------------------------------------------------------------------
__global__ __launch_bounds__(256, 3) void knn_fused_kernel(
    const float* __restrict__ xn, const float* __restrict__ sqc,
    const float* __restrict__ rp, u64* __restrict__ pko)
{
    __shared__ float shR[CC * 64];    // [c][r]   24 KB, persistent
    __shared__ float shC[CC * 64];    // [c][m]   24 KB, restaged per m-tile
    const int b    = blockIdx.z;
    const int part = blockIdx.y;
    const int r0   = blockIdx.x * 64;
    const int tid  = threadIdx.x;
    const int tx = tid & 15;          // 16 col groups of 4
    const int ty = tid >> 4;          // 16 row groups of 4
    const float* xb  = xn  + (size_t)b * CC * NN;
    const float* sqb = sqc + (size_t)b * NN;

    // stage 64-row slab of xn (float4, coalesced); visible after 1st barrier
    #pragma unroll
    for (int i = 0; i < 6; i++) {
        int idx = tid + i * 256;              // 1536 float4s
        int c = idx >> 4, r4 = (idx & 15) << 2;
        *(float4*)&shR[c * 64 + r4] = *(const float4*)&xb[(size_t)c * NN + r0 + r4];
    }

    u64 kk[4][9];
    #pragma unroll
    for (int i = 0; i < 4; i++)
        #pragma unroll
        for (int j = 0; j < 9; j++) kk[i][j] = 0xFFFFFFFFFFFFFFFFull;

    const int rA = r0 + ty * 4;           // first of this thread's 4 rows

    // prefetch shC data for mt=0 into registers
    float4 nx[6];
    {
        const int m0 = part * PARTS * 64;
        #pragma unroll
        for (int i = 0; i < 6; i++) {
            int idx = tid + i * 256;
            int c = idx >> 4, m4 = (idx & 15) << 2;
            nx[i] = *(const float4*)&xb[(size_t)c * NN + m0 + m4];
        }
    }

    for (int mt = 0; mt < PARTS; mt++) {
        const int m0 = (part * PARTS + mt) * 64;

        __syncthreads();   // (A) all reads of shC for mt-1 complete
        #pragma unroll
        for (int i = 0; i < 6; i++) {
            int idx = tid + i * 256;
            int c = idx >> 4, m4 = (idx & 15) << 2;
            *(float4*)&shC[c * 64 + m4] = nx[i];
        }
        // issue next-tile global loads now; latency hides under FMA loop
        if (mt + 1 < PARTS) {
            const int m0n = m0 + 64;
            #pragma unroll
            for (int i = 0; i < 6; i++) {
                int idx = tid + i * 256;
                int c = idx >> 4, m4 = (idx & 15) << 2;
                nx[i] = *(const float4*)&xb[(size_t)c * NN + m0n + m4];
            }
        }
        // rp/sq for this mt: issued here, consumed in epilogue
        const float4 sqv = *(const float4*)&sqb[m0 + tx * 4];
        const float4 rp0 = *(const float4*)&rp[(size_t)(rA + 0) * NN + m0 + tx * 4];
        const float4 rp1 = *(const float4*)&rp[(size_t)(rA + 1) * NN + m0 + tx * 4];
        const float4 rp2 = *(const float4*)&rp[(size_t)(rA + 2) * NN + m0 + tx * 4];
        const float4 rp3 = *(const float4*)&rp[(size_t)(rA + 3) * NN + m0 + tx * 4];
        __syncthreads();   // (B) shC staged

        float acc[4][4] = {{0.f}};
        #pragma unroll 4
        for (int c = 0; c < CC; c++) {
            const float4 rv = *(const float4*)&shR[c * 64 + ty * 4];
            const float4 cv = *(const float4*)&shC[c * 64 + tx * 4];
            const float r_[4] = {rv.x, rv.y, rv.z, rv.w};
            const float c_[4] = {cv.x, cv.y, cv.z, cv.w};
            #pragma unroll
            for (int i = 0; i < 4; i++)
                #pragma unroll
                for (int j = 0; j < 4; j++)
                    acc[i][j] = fmaf(r_[i], c_[j], acc[i][j]);
        }

        // epilogue: distances -> u64 keys -> per-thread top-9 per row
        const float sq_[4] = {sqv.x, sqv.y, sqv.z, sqv.w};
        const float rpv[4][4] = {{rp0.x, rp0.y, rp0.z, rp0.w},
                                 {rp1.x, rp1.y, rp1.z, rp1.w},
                                 {rp2.x, rp2.y, rp2.z, rp2.w},
                                 {rp3.x, rp3.y, rp3.z, rp3.w}};
        #pragma unroll
        for (int i = 0; i < 4; i++)
            #pragma unroll
            for (int j = 0; j < 4; j++) {
                const int m = m0 + tx * 4 + j;
                ins9u(kk[i], dkey(fmaf(-2.f, acc[i][j], sq_[j] + rpv[i][j]), m));
            }
    }

    // tournament merge across the aligned 16-lane col-group per row:
    // 9 rounds of butterfly-min over lane heads, pop unique winner.
    #pragma unroll
    for (int i = 0; i < 4; i++) {
        const size_t base = ((size_t)(b * NN + rA + i) * PARTS + part) * KNB;
        #pragma unroll
        for (int k = 0; k < 9; k++) {
            u64 w = kk[i][0];
            #pragma unroll
            for (int off = 1; off < 16; off <<= 1) {
                unsigned int lo = __shfl_xor((unsigned int)w, off);
                unsigned int hi = __shfl_xor((unsigned int)(w >> 32), off);
                u64 o = ((u64)hi << 32) | lo;
                w = (o < w) ? o : w;
            }
            if (kk[i][0] == w) {          // unique winner (keys contain m)
                #pragma unroll
                for (int j = 0; j < 8; j++) kk[i][j] = kk[i][j + 1];
                kk[i][8] = 0xFFFFFFFFFFFFFFFFull;
            }
            if (tx == 0) pko[base + k] = w;
        }
    }
}

// ---------------------------------------------------------------------------
// Merge PARTS sorted 9-lists (u64 keys) per (b,n) -> final nn_idx
// ---------------------------------------------------------------------------
__global__ __launch_bounds__(256) void knn_merge_kernel(
    const u64* __restrict__ pko, int* __restrict__ nn_idx)
{
    const int g = blockIdx.x * 256 + threadIdx.x;   // over B*N
    if (g >= BB * NN) return;
    u64 kk[9];
    #pragma unroll
    for (int j = 0; j < 9; j++) kk[j] = 0xFFFFFFFFFFFFFFFFull;
    const u64* v = pko + (size_t)g * PARTS * KNB;
    for (int p = 0; p < PARTS; p++)
        #pragma unroll
        for (int j = 0; j < 9; j++)
            ins9u(kk, v[p * KNB + j]);
    #pragma unroll
    for (int j = 0; j < 9; j++)
        nn_idx[(size_t)g * KNB + j] = (int)(kk[j] & 0xFFFFFFFFu);
}

// ---------------------------------------------------------------------------
// Max-relative gather + channel interleave
// ---------------------------------------------------------------------------
__global__ __launch_bounds__(256) void gather_kernel(
    const float* __restrict__ xf, const int* __restrict__ nn_idx,
    float* __restrict__ y)
{
    const size_t g = (size_t)blockIdx.x * 256 + threadIdx.x;   // over B*C*N
    const int n  = (int)(g % NN);
    const int bc = (int)(g / NN);
    const int c  = bc % CC;
    const int b  = bc / CC;
    const float* row = xf + (size_t)(b * CC + c) * NN;
    const float xi = row[n];
    const int* id = nn_idx + ((size_t)b * NN + n) * KNB;
    float mx = -FLT_MAX_;
    #pragma unroll
    for (int k = 0; k < KNB; k++) mx = fmaxf(mx, row[id[k]] - xi);
    float* o = y + ((size_t)b * 2 * CC + 2 * c) * NN + n;
    o[0]  = xi;
    o[NN] = mx;
}

// ---------------------------------------------------------------------------
// Host-side orchestration
// ---------------------------------------------------------------------------
static void conv1(const float* in, const float* w, const float* b, float* out,
                  int K, int O, hipStream_t s)
{
    dim3 grid(NN / 64, (O + 63) / 64, BB);
    conv1_kernel<<<grid, 256, 0, s>>>(in, w, b, out, K, O);
}
static void inorm(const float* in, float* out, const float* res, int ch, int act,
                  hipStream_t s)
{
    inorm_kernel<<<BB * ch, 256, 0, s>>>(in, out, res, act);
}

struct GrapherP {
    const float *fc1w, *fc1b, *mrw, *mrb, *fc2w, *fc2b;
};

static void run_grapher(const float* in, const float* rp, const GrapherP& p,
                        float* outCur, float* bufA, float* bufB, float* xnb,
                        float* sqc, int* idx, hipStream_t s)
{
    conv1(in, p.fc1w, p.fc1b, bufA, CC, CC, s);
    inorm(bufA, bufB, nullptr, CC, 0, s);                         // xf
    colnorm_kernel<<<(BB * NN) / 256, 256, 0, s>>>(bufB, xnb, sqc);
    // partial-key scratch lives in bufA (free until gather writes it):
    // B*N*PARTS*9 u64 = 12.6 MB << P4 floats
    u64* pko = (u64*)bufA;
    knn_fused_kernel<<<dim3(NN / 64, PARTS, BB), 256, 0, s>>>(xnb, sqc, rp, pko);
    knn_merge_kernel<<<(BB * NN + 255) / 256, 256, 0, s>>>(pko, idx);
    gather_kernel<<<(BB * CC * NN) / 256, 256, 0, s>>>(bufB, idx, bufA);  // 2C
    conv1(bufA, p.mrw, p.mrb, bufB, 2 * CC, 2 * CC, s);
    inorm(bufB, bufA, nullptr, 2 * CC, 1, s);                     // gelu
    conv1(bufA, p.fc2w, p.fc2b, bufB, 2 * CC, CC, s);
    inorm(bufB, outCur, in, CC, 0, s);                            // + shortcut
}

static void run_ffn(const float* in, const float* w1, const float* b1,
                    const float* w2, const float* b2,
                    float* outCur, float* bufA, float* bufB, hipStream_t s)
{
    conv1(in, w1, b1, bufA, CC, 4 * CC, s);
    inorm(bufA, bufB, nullptr, 4 * CC, 1, s);                     // gelu
    conv1(bufB, w2, b2, bufA, 2 * CC * 2, CC, s);
    inorm(bufA, outCur, in, CC, 0, s);                            // + shortcut
}

extern "C" void kernel_launch(void* const* d_in, const int* in_sizes, int n_in,
                              void* d_out, int out_size, void* d_ws, size_t ws_size,
                              hipStream_t stream)
{
    const float* x  = (const float*)d_in[0];
    const float* rp = (const float*)d_in[1];
    GrapherP g1 = {(const float*)d_in[2],  (const float*)d_in[3],
                   (const float*)d_in[4],  (const float*)d_in[5],
                   (const float*)d_in[6],  (const float*)d_in[7]};
    GrapherP g2 = {(const float*)d_in[8],  (const float*)d_in[9],
                   (const float*)d_in[10], (const float*)d_in[11],
                   (const float*)d_in[12], (const float*)d_in[13]};
    const float* f1w1 = (const float*)d_in[14]; const float* f1b1 = (const float*)d_in[15];
    const float* f1w2 = (const float*)d_in[16]; const float* f1b2 = (const float*)d_in[17];
    const float* f2w1 = (const float*)d_in[18]; const float* f2b1 = (const float*)d_in[19];
    const float* f2w2 = (const float*)d_in[20]; const float* f2b2 = (const float*)d_in[21];
    float* out = (float*)d_out;

    const size_t P  = (size_t)BB * CC * NN;     // 2,408,448 floats
    const size_t P4 = 4 * P;
    float* ws   = (float*)d_ws;
    float* bufA = ws;                 // P4
    float* bufB = bufA + P4;          // P4
    float* xnb  = bufB + P4;          // P
    float* cur0 = xnb + P;            // P
    float* cur1 = cur0 + P;           // P
    float* sqc  = cur1 + P;           // B*N
    int*   idx  = (int*)(sqc + (size_t)BB * NN);   // B*N*9 ints

    run_grapher(x, rp, g1, cur0, bufA, bufB, xnb, sqc, idx, stream);
    run_ffn(cur0, f1w1, f1b1, f1w2, f1b2, cur1, bufA, bufB, stream);
    inorm(cur1, cur0, nullptr, CC, 2, stream);
    run_grapher(cur0, rp, g2, cur1, bufA, bufB, xnb, sqc, idx, stream);
    run_ffn(cur1, f2w1, f2b1, f2w2, f2b2, cur0, bufA, bufB, stream);
    inorm(cur0, out, x, CC, 0, stream);
    (void)in_sizes; (void)n_in; (void)out_size; (void)ws_size;
}

// Round 8
// 1449.532 us; speedup vs baseline: 1.0409x; 1.0233x over previous
//
#include <hip/hip_runtime.h>
#include <math.h>

#define NN 3136      // H*W = 56*56
#define CC 96
#define BB 8
#define KNB 9
#define PARTS 7      // m-range split: 7 parts x 7 mt x 64 = 3136 cols
#define FLT_MAX_ 3.402823466e+38f
typedef unsigned long long u64;

// ---------------------------------------------------------------------------
// 1x1 conv as batched GEMM (baseline version, known-good)
// ---------------------------------------------------------------------------
__global__ __launch_bounds__(256) void conv1_kernel(
    const float* __restrict__ in, const float* __restrict__ w,
    const float* __restrict__ bias, float* __restrict__ out, int K, int O)
{
    __shared__ float sW[16][64];   // [kk][o]
    __shared__ float sX[16][64];   // [kk][n]
    const int b  = blockIdx.z;
    const int n0 = blockIdx.x * 64;
    const int o0 = blockIdx.y * 64;
    const int tid = threadIdx.x;
    const int tx = tid & 15, ty = tid >> 4;
    const float* inb = in + (size_t)b * K * NN;

    float acc[4][4] = {{0.f}};

    for (int kb = 0; kb < K; kb += 16) {
        __syncthreads();
        {
            int o  = tid >> 2;
            int k4 = (tid & 3) << 2;
            float4 wv = make_float4(0.f, 0.f, 0.f, 0.f);
            if (o0 + o < O)
                wv = *(const float4*)&w[(size_t)(o0 + o) * K + kb + k4];
            sW[k4 + 0][o] = wv.x; sW[k4 + 1][o] = wv.y;
            sW[k4 + 2][o] = wv.z; sW[k4 + 3][o] = wv.w;
        }
        #pragma unroll
        for (int i = 0; i < 4; i++) {
            int e = tid + i * 256;
            int kk = e >> 6, n2 = e & 63;
            sX[kk][n2] = inb[(size_t)(kb + kk) * NN + n0 + n2];
        }
        __syncthreads();
        #pragma unroll
        for (int kk = 0; kk < 16; kk++) {
            const float4 av = *(const float4*)&sW[kk][ty << 2];
            const float4 xv = *(const float4*)&sX[kk][tx << 2];
            float a_[4] = {av.x, av.y, av.z, av.w};
            float x_[4] = {xv.x, xv.y, xv.z, xv.w};
            #pragma unroll
            for (int i = 0; i < 4; i++)
                #pragma unroll
                for (int j = 0; j < 4; j++)
                    acc[i][j] = fmaf(a_[i], x_[j], acc[i][j]);
        }
    }
    #pragma unroll
    for (int i = 0; i < 4; i++) {
        int o = o0 + (ty << 2) + i;
        if (o < O) {
            float bo = bias[o];
            float4 v = make_float4(acc[i][0] + bo, acc[i][1] + bo,
                                   acc[i][2] + bo, acc[i][3] + bo);
            *(float4*)&out[((size_t)b * O + o) * NN + n0 + (tx << 2)] = v;
        }
    }
}

// ---------------------------------------------------------------------------
// Instance norm over N per (b,c) row; act: 0 none, 1 gelu, 2 relu
// ---------------------------------------------------------------------------
__global__ __launch_bounds__(256) void inorm_kernel(
    const float* __restrict__ in, float* __restrict__ out,
    const float* __restrict__ res, int act)
{
    const int row = blockIdx.x;
    const float* x = in + (size_t)row * NN;
    const int tid = threadIdx.x;

    float v[13];
    float s = 0.f;
    #pragma unroll
    for (int i = 0; i < 13; i++) {
        int idx = tid + i * 256;
        v[i] = (idx < NN) ? x[idx] : 0.f;
        s += v[i];
    }
    __shared__ float red[4];
    #pragma unroll
    for (int off = 32; off > 0; off >>= 1) s += __shfl_down(s, off);
    if ((tid & 63) == 0) red[tid >> 6] = s;
    __syncthreads();
    const float mean = (red[0] + red[1] + red[2] + red[3]) * (1.f / (float)NN);

    float s2 = 0.f;
    #pragma unroll
    for (int i = 0; i < 13; i++) {
        int idx = tid + i * 256;
        if (idx < NN) { float d = v[i] - mean; s2 = fmaf(d, d, s2); }
    }
    #pragma unroll
    for (int off = 32; off > 0; off >>= 1) s2 += __shfl_down(s2, off);
    __syncthreads();
    if ((tid & 63) == 0) red[tid >> 6] = s2;
    __syncthreads();
    const float var = (red[0] + red[1] + red[2] + red[3]) * (1.f / (float)NN);
    const float rs = rsqrtf(var + 1e-5f);

    float* o = out + (size_t)row * NN;
    const float* rr = res ? (res + (size_t)row * NN) : nullptr;
    #pragma unroll
    for (int i = 0; i < 13; i++) {
        int idx = tid + i * 256;
        if (idx < NN) {
            float y = (v[i] - mean) * rs;
            if (act == 1)      y = 0.5f * y * (1.f + erff(y * 0.70710678118654752f));
            else if (act == 2) y = fmaxf(y, 0.f);
            if (rr) y += rr[idx];
            o[idx] = y;
        }
    }
}

// ---------------------------------------------------------------------------
// Column (channel) L2-normalize + sq[b,n] = sum_c xn^2
// ---------------------------------------------------------------------------
__global__ __launch_bounds__(256) void colnorm_kernel(
    const float* __restrict__ xf, float* __restrict__ xn,
    float* __restrict__ sqc)
{
    const int g = blockIdx.x * 256 + threadIdx.x;   // over B*N
    const int b = g / NN;
    const int n = g - b * NN;
    const float* p = xf + (size_t)b * CC * NN + n;
    float* q = xn + (size_t)b * CC * NN + n;

    float s = 0.f;
    for (int c = 0; c < CC; c++) { float t = p[(size_t)c * NN]; s = fmaf(t, t, s); }
    const float den = fmaxf(sqrtf(s), 1e-12f);

    float sq = 0.f;
    for (int c = 0; c < CC; c++) {
        float t = p[(size_t)c * NN] / den;
        q[(size_t)c * NN] = t;
        sq = fmaf(t, t, sq);
    }
    sqc[g] = sq;
}

// ---------------------------------------------------------------------------
// u64-key top-9: key = (ord(dist) << 32) | m.  min-u64 == (min d, then min m)
// == reference top_k tie-break (stable, lower index first).
// ---------------------------------------------------------------------------
__device__ __forceinline__ u64 dkey(float d, int m)
{
    unsigned int ub = __float_as_uint(d);
    ub ^= (unsigned int)(((int)ub) >> 31) | 0x80000000u;
    return ((u64)ub << 32) | (unsigned int)m;
}
__device__ __forceinline__ void ins9u(u64 (&kk)[9], u64 key)
{
    if (key < kk[8]) {
        kk[8] = key;
        #pragma unroll
        for (int j = 8; j > 0; --j) {
            if (kk[j] < kk[j - 1]) {
                u64 t = kk[j]; kk[j] = kk[j - 1]; kk[j - 1] = t;
            }
        }
    }
}

// ---------------------------------------------------------------------------
// Fused distance GEMM + top-9 select (v4).
// v3's kk[4][9] (288 B, loop-indexed) failed SROA -> scratch (WRITE 407 MB;
// launch_bounds didn't help because it was never a regalloc cap issue).
// v4 = identical 4x4-tile structure with all aggregates flattened to NAMED
// arrays/scalars (kk0..kk3 u64[9] like proven v2; acc00..acc33; nx0..nx5) so
// SROA promotes everything. No runtime-variable outer indexing anywhere.
// grid: (NN/64, PARTS, BB), 256 threads.
// ---------------------------------------------------------------------------
#define EPI_ROW(KK, A0, A1, A2, A3, RPV)                                   \
    ins9u(KK, dkey(fmaf(-2.f, A0, sqv.x + RPV.x), mb + 0));                \
    ins9u(KK, dkey(fmaf(-2.f, A1, sqv.y + RPV.y), mb + 1));                \
    ins9u(KK, dkey(fmaf(-2.f, A2, sqv.z + RPV.z), mb + 2));                \
    ins9u(KK, dkey(fmaf(-2.f, A3, sqv.w + RPV.w), mb + 3));

#define MERGE_ROW(KK, ROW)                                                 \
    {                                                                      \
        const size_t base_ = ((size_t)(b * NN + (ROW)) * PARTS + part) * KNB; \
        _Pragma("unroll")                                                  \
        for (int k = 0; k < 9; k++) {                                      \
            u64 w = KK[0];                                                 \
            _Pragma("unroll")                                              \
            for (int off = 1; off < 16; off <<= 1) {                       \
                unsigned int lo = __shfl_xor((unsigned int)w, off);        \
                unsigned int hi = __shfl_xor((unsigned int)(w >> 32), off);\
                u64 o_ = ((u64)hi << 32) | lo;                             \
                w = (o_ < w) ? o_ : w;                                     \
            }                                                              \
            if (KK[0] == w) {                                              \
                _Pragma("unroll")                                          \
                for (int j = 0; j < 8; j++) KK[j] = KK[j + 1];             \
                KK[8] = 0xFFFFFFFFFFFFFFFFull;                             \
            }                                                              \
            if (tx == 0) pko[base_ + k] = w;                               \
        }                                                                  \
    }

__global__ __launch_bounds__(256, 3) void knn_fused_kernel(
    const float* __restrict__ xn, const float* __restrict__ sqc,
    const float* __restrict__ rp, u64* __restrict__ pko)
{
    __shared__ float shR[CC * 64];    // [c][r]   24 KB, persistent
    __shared__ float shC[CC * 64];    // [c][m]   24 KB, restaged per m-tile
    const int b    = blockIdx.z;
    const int part = blockIdx.y;
    const int r0   = blockIdx.x * 64;
    const int tid  = threadIdx.x;
    const int tx = tid & 15;          // 16 col groups of 4
    const int ty = tid >> 4;          // 16 row groups of 4
    const float* xb  = xn  + (size_t)b * CC * NN;
    const float* sqb = sqc + (size_t)b * NN;

    // staging coordinates: (tid + i*256)>>4 = cb + 16*i ; (tid+i*256)&15 = tid&15
    const int cb = tid >> 4;          // base channel 0..15
    const int m4 = (tid & 15) << 2;   // column byte-group 0..60

    // stage 64-row slab of xn (96 channels = cb + 16*i, i=0..5)
    *(float4*)&shR[(cb +  0) * 64 + m4] = *(const float4*)&xb[(size_t)(cb +  0) * NN + r0 + m4];
    *(float4*)&shR[(cb + 16) * 64 + m4] = *(const float4*)&xb[(size_t)(cb + 16) * NN + r0 + m4];
    *(float4*)&shR[(cb + 32) * 64 + m4] = *(const float4*)&xb[(size_t)(cb + 32) * NN + r0 + m4];
    *(float4*)&shR[(cb + 48) * 64 + m4] = *(const float4*)&xb[(size_t)(cb + 48) * NN + r0 + m4];
    *(float4*)&shR[(cb + 64) * 64 + m4] = *(const float4*)&xb[(size_t)(cb + 64) * NN + r0 + m4];
    *(float4*)&shR[(cb + 80) * 64 + m4] = *(const float4*)&xb[(size_t)(cb + 80) * NN + r0 + m4];

    u64 kk0[9], kk1[9], kk2[9], kk3[9];
    #pragma unroll
    for (int j = 0; j < 9; j++) {
        kk0[j] = 0xFFFFFFFFFFFFFFFFull; kk1[j] = 0xFFFFFFFFFFFFFFFFull;
        kk2[j] = 0xFFFFFFFFFFFFFFFFull; kk3[j] = 0xFFFFFFFFFFFFFFFFull;
    }

    const int rA = r0 + ty * 4;           // first of this thread's 4 rows

    // prefetch shC data for mt=0 into named registers
    float4 nx0, nx1, nx2, nx3, nx4, nx5;
    {
        const int m0p = part * PARTS * 64;
        nx0 = *(const float4*)&xb[(size_t)(cb +  0) * NN + m0p + m4];
        nx1 = *(const float4*)&xb[(size_t)(cb + 16) * NN + m0p + m4];
        nx2 = *(const float4*)&xb[(size_t)(cb + 32) * NN + m0p + m4];
        nx3 = *(const float4*)&xb[(size_t)(cb + 48) * NN + m0p + m4];
        nx4 = *(const float4*)&xb[(size_t)(cb + 64) * NN + m0p + m4];
        nx5 = *(const float4*)&xb[(size_t)(cb + 80) * NN + m0p + m4];
    }

    for (int mt = 0; mt < PARTS; mt++) {
        const int m0 = (part * PARTS + mt) * 64;

        __syncthreads();   // (A) all reads of shC for mt-1 complete
        *(float4*)&shC[(cb +  0) * 64 + m4] = nx0;
        *(float4*)&shC[(cb + 16) * 64 + m4] = nx1;
        *(float4*)&shC[(cb + 32) * 64 + m4] = nx2;
        *(float4*)&shC[(cb + 48) * 64 + m4] = nx3;
        *(float4*)&shC[(cb + 64) * 64 + m4] = nx4;
        *(float4*)&shC[(cb + 80) * 64 + m4] = nx5;
        // issue next-tile global loads now; latency hides under FMA loop
        if (mt + 1 < PARTS) {
            const int m0n = m0 + 64;
            nx0 = *(const float4*)&xb[(size_t)(cb +  0) * NN + m0n + m4];
            nx1 = *(const float4*)&xb[(size_t)(cb + 16) * NN + m0n + m4];
            nx2 = *(const float4*)&xb[(size_t)(cb + 32) * NN + m0n + m4];
            nx3 = *(const float4*)&xb[(size_t)(cb + 48) * NN + m0n + m4];
            nx4 = *(const float4*)&xb[(size_t)(cb + 64) * NN + m0n + m4];
            nx5 = *(const float4*)&xb[(size_t)(cb + 80) * NN + m0n + m4];
        }
        // rp/sq for this mt: issued here, consumed in epilogue
        const float4 sqv = *(const float4*)&sqb[m0 + tx * 4];
        const float4 rp0 = *(const float4*)&rp[(size_t)(rA + 0) * NN + m0 + tx * 4];
        const float4 rp1 = *(const float4*)&rp[(size_t)(rA + 1) * NN + m0 + tx * 4];
        const float4 rp2 = *(const float4*)&rp[(size_t)(rA + 2) * NN + m0 + tx * 4];
        const float4 rp3 = *(const float4*)&rp[(size_t)(rA + 3) * NN + m0 + tx * 4];
        __syncthreads();   // (B) shC staged

        float acc00 = 0.f, acc01 = 0.f, acc02 = 0.f, acc03 = 0.f;
        float acc10 = 0.f, acc11 = 0.f, acc12 = 0.f, acc13 = 0.f;
        float acc20 = 0.f, acc21 = 0.f, acc22 = 0.f, acc23 = 0.f;
        float acc30 = 0.f, acc31 = 0.f, acc32 = 0.f, acc33 = 0.f;
        #pragma unroll 4
        for (int c = 0; c < CC; c++) {
            const float4 rv = *(const float4*)&shR[c * 64 + ty * 4];
            const float4 cv = *(const float4*)&shC[c * 64 + tx * 4];
            acc00 = fmaf(rv.x, cv.x, acc00);
            acc01 = fmaf(rv.x, cv.y, acc01);
            acc02 = fmaf(rv.x, cv.z, acc02);
            acc03 = fmaf(rv.x, cv.w, acc03);
            acc10 = fmaf(rv.y, cv.x, acc10);
            acc11 = fmaf(rv.y, cv.y, acc11);
            acc12 = fmaf(rv.y, cv.z, acc12);
            acc13 = fmaf(rv.y, cv.w, acc13);
            acc20 = fmaf(rv.z, cv.x, acc20);
            acc21 = fmaf(rv.z, cv.y, acc21);
            acc22 = fmaf(rv.z, cv.z, acc22);
            acc23 = fmaf(rv.z, cv.w, acc23);
            acc30 = fmaf(rv.w, cv.x, acc30);
            acc31 = fmaf(rv.w, cv.y, acc31);
            acc32 = fmaf(rv.w, cv.z, acc32);
            acc33 = fmaf(rv.w, cv.w, acc33);
        }

        // epilogue: distances -> u64 keys -> per-thread top-9 per row
        const int mb = m0 + tx * 4;
        EPI_ROW(kk0, acc00, acc01, acc02, acc03, rp0)
        EPI_ROW(kk1, acc10, acc11, acc12, acc13, rp1)
        EPI_ROW(kk2, acc20, acc21, acc22, acc23, rp2)
        EPI_ROW(kk3, acc30, acc31, acc32, acc33, rp3)
    }

    // tournament merge across the aligned 16-lane col-group per row
    MERGE_ROW(kk0, rA + 0)
    MERGE_ROW(kk1, rA + 1)
    MERGE_ROW(kk2, rA + 2)
    MERGE_ROW(kk3, rA + 3)
}

// ---------------------------------------------------------------------------
// Merge PARTS sorted 9-lists (u64 keys) per (b,n) -> final nn_idx
// ---------------------------------------------------------------------------
__global__ __launch_bounds__(256) void knn_merge_kernel(
    const u64* __restrict__ pko, int* __restrict__ nn_idx)
{
    const int g = blockIdx.x * 256 + threadIdx.x;   // over B*N
    if (g >= BB * NN) return;
    u64 kk[9];
    #pragma unroll
    for (int j = 0; j < 9; j++) kk[j] = 0xFFFFFFFFFFFFFFFFull;
    const u64* v = pko + (size_t)g * PARTS * KNB;
    for (int p = 0; p < PARTS; p++)
        #pragma unroll
        for (int j = 0; j < 9; j++)
            ins9u(kk, v[p * KNB + j]);
    #pragma unroll
    for (int j = 0; j < 9; j++)
        nn_idx[(size_t)g * KNB + j] = (int)(kk[j] & 0xFFFFFFFFu);
}

// ---------------------------------------------------------------------------
// Max-relative gather + channel interleave
// ---------------------------------------------------------------------------
__global__ __launch_bounds__(256) void gather_kernel(
    const float* __restrict__ xf, const int* __restrict__ nn_idx,
    float* __restrict__ y)
{
    const size_t g = (size_t)blockIdx.x * 256 + threadIdx.x;   // over B*C*N
    const int n  = (int)(g % NN);
    const int bc = (int)(g / NN);
    const int c  = bc % CC;
    const int b  = bc / CC;
    const float* row = xf + (size_t)(b * CC + c) * NN;
    const float xi = row[n];
    const int* id = nn_idx + ((size_t)b * NN + n) * KNB;
    float mx = -FLT_MAX_;
    #pragma unroll
    for (int k = 0; k < KNB; k++) mx = fmaxf(mx, row[id[k]] - xi);
    float* o = y + ((size_t)b * 2 * CC + 2 * c) * NN + n;
    o[0]  = xi;
    o[NN] = mx;
}

// ---------------------------------------------------------------------------
// Host-side orchestration
// ---------------------------------------------------------------------------
static void conv1(const float* in, const float* w, const float* b, float* out,
                  int K, int O, hipStream_t s)
{
    dim3 grid(NN / 64, (O + 63) / 64, BB);
    conv1_kernel<<<grid, 256, 0, s>>>(in, w, b, out, K, O);
}
static void inorm(const float* in, float* out, const float* res, int ch, int act,
                  hipStream_t s)
{
    inorm_kernel<<<BB * ch, 256, 0, s>>>(in, out, res, act);
}

struct GrapherP {
    const float *fc1w, *fc1b, *mrw, *mrb, *fc2w, *fc2b;
};

static void run_grapher(const float* in, const float* rp, const GrapherP& p,
                        float* outCur, float* bufA, float* bufB, float* xnb,
                        float* sqc, int* idx, hipStream_t s)
{
    conv1(in, p.fc1w, p.fc1b, bufA, CC, CC, s);
    inorm(bufA, bufB, nullptr, CC, 0, s);                         // xf
    colnorm_kernel<<<(BB * NN) / 256, 256, 0, s>>>(bufB, xnb, sqc);
    // partial-key scratch lives in bufA (free until gather writes it):
    // B*N*PARTS*9 u64 = 12.6 MB << P4 floats
    u64* pko = (u64*)bufA;
    knn_fused_kernel<<<dim3(NN / 64, PARTS, BB), 256, 0, s>>>(xnb, sqc, rp, pko);
    knn_merge_kernel<<<(BB * NN + 255) / 256, 256, 0, s>>>(pko, idx);
    gather_kernel<<<(BB * CC * NN) / 256, 256, 0, s>>>(bufB, idx, bufA);  // 2C
    conv1(bufA, p.mrw, p.mrb, bufB, 2 * CC, 2 * CC, s);
    inorm(bufB, bufA, nullptr, 2 * CC, 1, s);                     // gelu
    conv1(bufA, p.fc2w, p.fc2b, bufB, 2 * CC, CC, s);
    inorm(bufB, outCur, in, CC, 0, s);                            // + shortcut
}

static void run_ffn(const float* in, const float* w1, const float* b1,
                    const float* w2, const float* b2,
                    float* outCur, float* bufA, float* bufB, hipStream_t s)
{
    conv1(in, w1, b1, bufA, CC, 4 * CC, s);
    inorm(bufA, bufB, nullptr, 4 * CC, 1, s);                     // gelu
    conv1(bufB, w2, b2, bufA, 2 * CC * 2, CC, s);
    inorm(bufA, outCur, in, CC, 0, s);                            // + shortcut
}

extern "C" void kernel_launch(void* const* d_in, const int* in_sizes, int n_in,
                              void* d_out, int out_size, void* d_ws, size_t ws_size,
                              hipStream_t stream)
{
    const float* x  = (const float*)d_in[0];
    const float* rp = (const float*)d_in[1];
    GrapherP g1 = {(const float*)d_in[2],  (const float*)d_in[3],
                   (const float*)d_in[4],  (const float*)d_in[5],
                   (const float*)d_in[6],  (const float*)d_in[7]};
    GrapherP g2 = {(const float*)d_in[8],  (const float*)d_in[9],
                   (const float*)d_in[10], (const float*)d_in[11],
                   (const float*)d_in[12], (const float*)d_in[13]};
    const float* f1w1 = (const float*)d_in[14]; const float* f1b1 = (const float*)d_in[15];
    const float* f1w2 = (const float*)d_in[16]; const float* f1b2 = (const float*)d_in[17];
    const float* f2w1 = (const float*)d_in[18]; const float* f2b1 = (const float*)d_in[19];
    const float* f2w2 = (const float*)d_in[20]; const float* f2b2 = (const float*)d_in[21];
    float* out = (float*)d_out;

    const size_t P  = (size_t)BB * CC * NN;     // 2,408,448 floats
    const size_t P4 = 4 * P;
    float* ws   = (float*)d_ws;
    float* bufA = ws;                 // P4
    float* bufB = bufA + P4;          // P4
    float* xnb  = bufB + P4;          // P
    float* cur0 = xnb + P;            // P
    float* cur1 = cur0 + P;           // P
    float* sqc  = cur1 + P;           // B*N
    int*   idx  = (int*)(sqc + (size_t)BB * NN);   // B*N*9 ints

    run_grapher(x, rp, g1, cur0, bufA, bufB, xnb, sqc, idx, stream);
    run_ffn(cur0, f1w1, f1b1, f1w2, f1b2, cur1, bufA, bufB, stream);
    inorm(cur1, cur0, nullptr, CC, 2, stream);
    run_grapher(cur0, rp, g2, cur1, bufA, bufB, xnb, sqc, idx, stream);
    run_ffn(cur1, f2w1, f2b1, f2w2, f2b2, cur0, bufA, bufB, stream);
    inorm(cur0, out, x, CC, 0, stream);
    (void)in_sizes; (void)n_in; (void)out_size; (void)ws_size;
}

// Round 9
// 1316.772 us; speedup vs baseline: 1.1458x; 1.1008x over previous
//
#include <hip/hip_runtime.h>
#include <math.h>

#define NN 3136      // H*W = 56*56
#define CC 96
#define BB 8
#define KNB 9
#define PARTS 7      // m-range split: 7 parts x 7 mt x 64 = 3136 cols
#define FLT_MAX_ 3.402823466e+38f
typedef unsigned long long u64;

// ---------------------------------------------------------------------------
// 1x1 conv as batched GEMM (baseline version, known-good)
// ---------------------------------------------------------------------------
__global__ __launch_bounds__(256) void conv1_kernel(
    const float* __restrict__ in, const float* __restrict__ w,
    const float* __restrict__ bias, float* __restrict__ out, int K, int O)
{
    __shared__ float sW[16][64];   // [kk][o]
    __shared__ float sX[16][64];   // [kk][n]
    const int b  = blockIdx.z;
    const int n0 = blockIdx.x * 64;
    const int o0 = blockIdx.y * 64;
    const int tid = threadIdx.x;
    const int tx = tid & 15, ty = tid >> 4;
    const float* inb = in + (size_t)b * K * NN;

    float acc[4][4] = {{0.f}};

    for (int kb = 0; kb < K; kb += 16) {
        __syncthreads();
        {
            int o  = tid >> 2;
            int k4 = (tid & 3) << 2;
            float4 wv = make_float4(0.f, 0.f, 0.f, 0.f);
            if (o0 + o < O)
                wv = *(const float4*)&w[(size_t)(o0 + o) * K + kb + k4];
            sW[k4 + 0][o] = wv.x; sW[k4 + 1][o] = wv.y;
            sW[k4 + 2][o] = wv.z; sW[k4 + 3][o] = wv.w;
        }
        #pragma unroll
        for (int i = 0; i < 4; i++) {
            int e = tid + i * 256;
            int kk = e >> 6, n2 = e & 63;
            sX[kk][n2] = inb[(size_t)(kb + kk) * NN + n0 + n2];
        }
        __syncthreads();
        #pragma unroll
        for (int kk = 0; kk < 16; kk++) {
            const float4 av = *(const float4*)&sW[kk][ty << 2];
            const float4 xv = *(const float4*)&sX[kk][tx << 2];
            float a_[4] = {av.x, av.y, av.z, av.w};
            float x_[4] = {xv.x, xv.y, xv.z, xv.w};
            #pragma unroll
            for (int i = 0; i < 4; i++)
                #pragma unroll
                for (int j = 0; j < 4; j++)
                    acc[i][j] = fmaf(a_[i], x_[j], acc[i][j]);
        }
    }
    #pragma unroll
    for (int i = 0; i < 4; i++) {
        int o = o0 + (ty << 2) + i;
        if (o < O) {
            float bo = bias[o];
            float4 v = make_float4(acc[i][0] + bo, acc[i][1] + bo,
                                   acc[i][2] + bo, acc[i][3] + bo);
            *(float4*)&out[((size_t)b * O + o) * NN + n0 + (tx << 2)] = v;
        }
    }
}

// ---------------------------------------------------------------------------
// Instance norm over N per (b,c) row; act: 0 none, 1 gelu, 2 relu
// ---------------------------------------------------------------------------
__global__ __launch_bounds__(256) void inorm_kernel(
    const float* __restrict__ in, float* __restrict__ out,
    const float* __restrict__ res, int act)
{
    const int row = blockIdx.x;
    const float* x = in + (size_t)row * NN;
    const int tid = threadIdx.x;

    float v[13];
    float s = 0.f;
    #pragma unroll
    for (int i = 0; i < 13; i++) {
        int idx = tid + i * 256;
        v[i] = (idx < NN) ? x[idx] : 0.f;
        s += v[i];
    }
    __shared__ float red[4];
    #pragma unroll
    for (int off = 32; off > 0; off >>= 1) s += __shfl_down(s, off);
    if ((tid & 63) == 0) red[tid >> 6] = s;
    __syncthreads();
    const float mean = (red[0] + red[1] + red[2] + red[3]) * (1.f / (float)NN);

    float s2 = 0.f;
    #pragma unroll
    for (int i = 0; i < 13; i++) {
        int idx = tid + i * 256;
        if (idx < NN) { float d = v[i] - mean; s2 = fmaf(d, d, s2); }
    }
    #pragma unroll
    for (int off = 32; off > 0; off >>= 1) s2 += __shfl_down(s2, off);
    __syncthreads();
    if ((tid & 63) == 0) red[tid >> 6] = s2;
    __syncthreads();
    const float var = (red[0] + red[1] + red[2] + red[3]) * (1.f / (float)NN);
    const float rs = rsqrtf(var + 1e-5f);

    float* o = out + (size_t)row * NN;
    const float* rr = res ? (res + (size_t)row * NN) : nullptr;
    #pragma unroll
    for (int i = 0; i < 13; i++) {
        int idx = tid + i * 256;
        if (idx < NN) {
            float y = (v[i] - mean) * rs;
            if (act == 1)      y = 0.5f * y * (1.f + erff(y * 0.70710678118654752f));
            else if (act == 2) y = fmaxf(y, 0.f);
            if (rr) y += rr[idx];
            o[idx] = y;
        }
    }
}

// ---------------------------------------------------------------------------
// Column (channel) L2-normalize + sq[b,n] = sum_c xn^2
// ---------------------------------------------------------------------------
__global__ __launch_bounds__(256) void colnorm_kernel(
    const float* __restrict__ xf, float* __restrict__ xn,
    float* __restrict__ sqc)
{
    const int g = blockIdx.x * 256 + threadIdx.x;   // over B*N
    const int b = g / NN;
    const int n = g - b * NN;
    const float* p = xf + (size_t)b * CC * NN + n;
    float* q = xn + (size_t)b * CC * NN + n;

    float s = 0.f;
    for (int c = 0; c < CC; c++) { float t = p[(size_t)c * NN]; s = fmaf(t, t, s); }
    const float den = fmaxf(sqrtf(s), 1e-12f);

    float sq = 0.f;
    for (int c = 0; c < CC; c++) {
        float t = p[(size_t)c * NN] / den;
        q[(size_t)c * NN] = t;
        sq = fmaf(t, t, sq);
    }
    sqc[g] = sq;
}

// ---------------------------------------------------------------------------
// u64-key top-9: key = (ord(dist) << 32) | m.  min-u64 == (min d, then min m)
// == reference top_k tie-break (stable, lower index first).
// ---------------------------------------------------------------------------
__device__ __forceinline__ u64 dkey(float d, int m)
{
    unsigned int ub = __float_as_uint(d);
    ub ^= (unsigned int)(((int)ub) >> 31) | 0x80000000u;
    return ((u64)ub << 32) | (unsigned int)m;
}
__device__ __forceinline__ void ins9u(u64 (&kk)[9], u64 key)
{
    if (key < kk[8]) {
        kk[8] = key;
        #pragma unroll
        for (int j = 8; j > 0; --j) {
            if (kk[j] < kk[j - 1]) {
                u64 t = kk[j]; kk[j] = kk[j - 1]; kk[j - 1] = t;
            }
        }
    }
}

// ---------------------------------------------------------------------------
// Fused distance GEMM + top-9 select (v5 = proven v2 + reg-prefetch staging).
// v2 structure (2 rows x 8 cols/thread, kk0/kk1 promoted, 353us) with ONE
// change: shC staging register-prefetched (named float4 nx0..nx5), so only
// 6 ds_write_b128 sit between the barriers -- the global-load latency for
// m-tile mt+1 hides under the mt FMA loop. v3/v4's 4-list branch abandoned
// (2 consecutive rounds: kk[4][9] and 4 named lists both fail promotion).
// grid: (NN/64, PARTS, BB), 256 threads.
// ---------------------------------------------------------------------------
__global__ __launch_bounds__(256, 3) void knn_fused_kernel(
    const float* __restrict__ xn, const float* __restrict__ sqc,
    const float* __restrict__ rp, u64* __restrict__ pko)
{
    __shared__ float shR[CC * 64];    // [c][r]   24 KB, persistent
    __shared__ float shC[CC * 64];    // [c][m]   24 KB, restaged per m-tile
    const int b    = blockIdx.z;
    const int part = blockIdx.y;
    const int r0   = blockIdx.x * 64;
    const int tid  = threadIdx.x;
    const int tx = tid & 7;           // 8 col groups of 8
    const int ty = tid >> 3;          // 32 row groups of 2
    const float* xb  = xn  + (size_t)b * CC * NN;
    const float* sqb = sqc + (size_t)b * NN;

    // staging coords: channel cb + 16*i (i=0..5), column group m4
    const int cb = tid >> 4;          // 0..15
    const int m4 = (tid & 15) << 2;   // 0,4,...,60

    // stage 64-row slab of xn (float4, coalesced); visible after 1st barrier
    *(float4*)&shR[(cb +  0) * 64 + m4] = *(const float4*)&xb[(size_t)(cb +  0) * NN + r0 + m4];
    *(float4*)&shR[(cb + 16) * 64 + m4] = *(const float4*)&xb[(size_t)(cb + 16) * NN + r0 + m4];
    *(float4*)&shR[(cb + 32) * 64 + m4] = *(const float4*)&xb[(size_t)(cb + 32) * NN + r0 + m4];
    *(float4*)&shR[(cb + 48) * 64 + m4] = *(const float4*)&xb[(size_t)(cb + 48) * NN + r0 + m4];
    *(float4*)&shR[(cb + 64) * 64 + m4] = *(const float4*)&xb[(size_t)(cb + 64) * NN + r0 + m4];
    *(float4*)&shR[(cb + 80) * 64 + m4] = *(const float4*)&xb[(size_t)(cb + 80) * NN + r0 + m4];

    u64 kk0[9], kk1[9];
    #pragma unroll
    for (int j = 0; j < 9; j++) { kk0[j] = kk1[j] = 0xFFFFFFFFFFFFFFFFull; }

    const int rA = r0 + ty * 2;

    // prefetch shC data for mt=0 into named registers
    float4 nx0, nx1, nx2, nx3, nx4, nx5;
    {
        const int m0p = part * PARTS * 64;
        nx0 = *(const float4*)&xb[(size_t)(cb +  0) * NN + m0p + m4];
        nx1 = *(const float4*)&xb[(size_t)(cb + 16) * NN + m0p + m4];
        nx2 = *(const float4*)&xb[(size_t)(cb + 32) * NN + m0p + m4];
        nx3 = *(const float4*)&xb[(size_t)(cb + 48) * NN + m0p + m4];
        nx4 = *(const float4*)&xb[(size_t)(cb + 64) * NN + m0p + m4];
        nx5 = *(const float4*)&xb[(size_t)(cb + 80) * NN + m0p + m4];
    }

    for (int mt = 0; mt < PARTS; mt++) {
        const int m0 = (part * PARTS + mt) * 64;

        __syncthreads();   // (A) all reads of shC for mt-1 complete
        *(float4*)&shC[(cb +  0) * 64 + m4] = nx0;
        *(float4*)&shC[(cb + 16) * 64 + m4] = nx1;
        *(float4*)&shC[(cb + 32) * 64 + m4] = nx2;
        *(float4*)&shC[(cb + 48) * 64 + m4] = nx3;
        *(float4*)&shC[(cb + 64) * 64 + m4] = nx4;
        *(float4*)&shC[(cb + 80) * 64 + m4] = nx5;
        // issue next-tile global loads now; latency hides under FMA loop
        if (mt + 1 < PARTS) {
            const int m0n = m0 + 64;
            nx0 = *(const float4*)&xb[(size_t)(cb +  0) * NN + m0n + m4];
            nx1 = *(const float4*)&xb[(size_t)(cb + 16) * NN + m0n + m4];
            nx2 = *(const float4*)&xb[(size_t)(cb + 32) * NN + m0n + m4];
            nx3 = *(const float4*)&xb[(size_t)(cb + 48) * NN + m0n + m4];
            nx4 = *(const float4*)&xb[(size_t)(cb + 64) * NN + m0n + m4];
            nx5 = *(const float4*)&xb[(size_t)(cb + 80) * NN + m0n + m4];
        }
        // rp/sq for this mt: issued here, consumed in epilogue
        const float4 s0 = *(const float4*)&sqb[m0 + tx * 8];
        const float4 s1 = *(const float4*)&sqb[m0 + tx * 8 + 4];
        const float4 a0 = *(const float4*)&rp[(size_t)rA * NN + m0 + tx * 8];
        const float4 a1 = *(const float4*)&rp[(size_t)rA * NN + m0 + tx * 8 + 4];
        const float4 b0v = *(const float4*)&rp[(size_t)(rA + 1) * NN + m0 + tx * 8];
        const float4 b1v = *(const float4*)&rp[(size_t)(rA + 1) * NN + m0 + tx * 8 + 4];
        __syncthreads();   // (B) shC staged

        float acc0[8] = {0.f, 0.f, 0.f, 0.f, 0.f, 0.f, 0.f, 0.f};
        float acc1[8] = {0.f, 0.f, 0.f, 0.f, 0.f, 0.f, 0.f, 0.f};
        #pragma unroll 4
        for (int c = 0; c < CC; c++) {
            const float2 rv = *(const float2*)&shR[c * 64 + ty * 2];
            const float4 c0 = *(const float4*)&shC[c * 64 + tx * 8];
            const float4 c1 = *(const float4*)&shC[c * 64 + tx * 8 + 4];
            acc0[0] = fmaf(rv.x, c0.x, acc0[0]);
            acc0[1] = fmaf(rv.x, c0.y, acc0[1]);
            acc0[2] = fmaf(rv.x, c0.z, acc0[2]);
            acc0[3] = fmaf(rv.x, c0.w, acc0[3]);
            acc0[4] = fmaf(rv.x, c1.x, acc0[4]);
            acc0[5] = fmaf(rv.x, c1.y, acc0[5]);
            acc0[6] = fmaf(rv.x, c1.z, acc0[6]);
            acc0[7] = fmaf(rv.x, c1.w, acc0[7]);
            acc1[0] = fmaf(rv.y, c0.x, acc1[0]);
            acc1[1] = fmaf(rv.y, c0.y, acc1[1]);
            acc1[2] = fmaf(rv.y, c0.z, acc1[2]);
            acc1[3] = fmaf(rv.y, c0.w, acc1[3]);
            acc1[4] = fmaf(rv.y, c1.x, acc1[4]);
            acc1[5] = fmaf(rv.y, c1.y, acc1[5]);
            acc1[6] = fmaf(rv.y, c1.z, acc1[6]);
            acc1[7] = fmaf(rv.y, c1.w, acc1[7]);
        }

        // epilogue: distances -> u64 keys -> per-thread top-9
        const float sq_[8] = {s0.x, s0.y, s0.z, s0.w, s1.x, s1.y, s1.z, s1.w};
        const float rA_[8] = {a0.x, a0.y, a0.z, a0.w, a1.x, a1.y, a1.z, a1.w};
        const float rB_[8] = {b0v.x, b0v.y, b0v.z, b0v.w, b1v.x, b1v.y, b1v.z, b1v.w};
        #pragma unroll
        for (int j = 0; j < 8; j++) {
            const int m = m0 + tx * 8 + j;
            ins9u(kk0, dkey(fmaf(-2.f, acc0[j], sq_[j] + rA_[j]), m));
            ins9u(kk1, dkey(fmaf(-2.f, acc1[j], sq_[j] + rB_[j]), m));
        }
    }

    // tournament merge across the aligned 8-lane row-group (tx 0..7).
    const size_t base0 = ((size_t)(b * NN + rA)     * PARTS + part) * KNB;
    const size_t base1 = ((size_t)(b * NN + rA + 1) * PARTS + part) * KNB;
    #pragma unroll
    for (int k = 0; k < 9; k++) {
        u64 w = kk0[0];
        #pragma unroll
        for (int off = 1; off < 8; off <<= 1) {
            unsigned int lo = __shfl_xor((unsigned int)w, off);
            unsigned int hi = __shfl_xor((unsigned int)(w >> 32), off);
            u64 o = ((u64)hi << 32) | lo;
            w = (o < w) ? o : w;
        }
        if (kk0[0] == w) {           // unique winner (keys contain m)
            #pragma unroll
            for (int j = 0; j < 8; j++) kk0[j] = kk0[j + 1];
            kk0[8] = 0xFFFFFFFFFFFFFFFFull;
        }
        if (tx == 0) pko[base0 + k] = w;
    }
    #pragma unroll
    for (int k = 0; k < 9; k++) {
        u64 w = kk1[0];
        #pragma unroll
        for (int off = 1; off < 8; off <<= 1) {
            unsigned int lo = __shfl_xor((unsigned int)w, off);
            unsigned int hi = __shfl_xor((unsigned int)(w >> 32), off);
            u64 o = ((u64)hi << 32) | lo;
            w = (o < w) ? o : w;
        }
        if (kk1[0] == w) {
            #pragma unroll
            for (int j = 0; j < 8; j++) kk1[j] = kk1[j + 1];
            kk1[8] = 0xFFFFFFFFFFFFFFFFull;
        }
        if (tx == 0) pko[base1 + k] = w;
    }
}

// ---------------------------------------------------------------------------
// Merge PARTS sorted 9-lists (u64 keys) per (b,n) -> final nn_idx
// ---------------------------------------------------------------------------
__global__ __launch_bounds__(256) void knn_merge_kernel(
    const u64* __restrict__ pko, int* __restrict__ nn_idx)
{
    const int g = blockIdx.x * 256 + threadIdx.x;   // over B*N
    if (g >= BB * NN) return;
    u64 kk[9];
    #pragma unroll
    for (int j = 0; j < 9; j++) kk[j] = 0xFFFFFFFFFFFFFFFFull;
    const u64* v = pko + (size_t)g * PARTS * KNB;
    for (int p = 0; p < PARTS; p++)
        #pragma unroll
        for (int j = 0; j < 9; j++)
            ins9u(kk, v[p * KNB + j]);
    #pragma unroll
    for (int j = 0; j < 9; j++)
        nn_idx[(size_t)g * KNB + j] = (int)(kk[j] & 0xFFFFFFFFu);
}

// ---------------------------------------------------------------------------
// Max-relative gather + channel interleave
// ---------------------------------------------------------------------------
__global__ __launch_bounds__(256) void gather_kernel(
    const float* __restrict__ xf, const int* __restrict__ nn_idx,
    float* __restrict__ y)
{
    const size_t g = (size_t)blockIdx.x * 256 + threadIdx.x;   // over B*C*N
    const int n  = (int)(g % NN);
    const int bc = (int)(g / NN);
    const int c  = bc % CC;
    const int b  = bc / CC;
    const float* row = xf + (size_t)(b * CC + c) * NN;
    const float xi = row[n];
    const int* id = nn_idx + ((size_t)b * NN + n) * KNB;
    float mx = -FLT_MAX_;
    #pragma unroll
    for (int k = 0; k < KNB; k++) mx = fmaxf(mx, row[id[k]] - xi);
    float* o = y + ((size_t)b * 2 * CC + 2 * c) * NN + n;
    o[0]  = xi;
    o[NN] = mx;
}

// ---------------------------------------------------------------------------
// Host-side orchestration
// ---------------------------------------------------------------------------
static void conv1(const float* in, const float* w, const float* b, float* out,
                  int K, int O, hipStream_t s)
{
    dim3 grid(NN / 64, (O + 63) / 64, BB);
    conv1_kernel<<<grid, 256, 0, s>>>(in, w, b, out, K, O);
}
static void inorm(const float* in, float* out, const float* res, int ch, int act,
                  hipStream_t s)
{
    inorm_kernel<<<BB * ch, 256, 0, s>>>(in, out, res, act);
}

struct GrapherP {
    const float *fc1w, *fc1b, *mrw, *mrb, *fc2w, *fc2b;
};

static void run_grapher(const float* in, const float* rp, const GrapherP& p,
                        float* outCur, float* bufA, float* bufB, float* xnb,
                        float* sqc, int* idx, hipStream_t s)
{
    conv1(in, p.fc1w, p.fc1b, bufA, CC, CC, s);
    inorm(bufA, bufB, nullptr, CC, 0, s);                         // xf
    colnorm_kernel<<<(BB * NN) / 256, 256, 0, s>>>(bufB, xnb, sqc);
    // partial-key scratch lives in bufA (free until gather writes it):
    // B*N*PARTS*9 u64 = 12.6 MB << P4 floats
    u64* pko = (u64*)bufA;
    knn_fused_kernel<<<dim3(NN / 64, PARTS, BB), 256, 0, s>>>(xnb, sqc, rp, pko);
    knn_merge_kernel<<<(BB * NN + 255) / 256, 256, 0, s>>>(pko, idx);
    gather_kernel<<<(BB * CC * NN) / 256, 256, 0, s>>>(bufB, idx, bufA);  // 2C
    conv1(bufA, p.mrw, p.mrb, bufB, 2 * CC, 2 * CC, s);
    inorm(bufB, bufA, nullptr, 2 * CC, 1, s);                     // gelu
    conv1(bufA, p.fc2w, p.fc2b, bufB, 2 * CC, CC, s);
    inorm(bufB, outCur, in, CC, 0, s);                            // + shortcut
}

static void run_ffn(const float* in, const float* w1, const float* b1,
                    const float* w2, const float* b2,
                    float* outCur, float* bufA, float* bufB, hipStream_t s)
{
    conv1(in, w1, b1, bufA, CC, 4 * CC, s);
    inorm(bufA, bufB, nullptr, 4 * CC, 1, s);                     // gelu
    conv1(bufB, w2, b2, bufA, 2 * CC * 2, CC, s);
    inorm(bufA, outCur, in, CC, 0, s);                            // + shortcut
}

extern "C" void kernel_launch(void* const* d_in, const int* in_sizes, int n_in,
                              void* d_out, int out_size, void* d_ws, size_t ws_size,
                              hipStream_t stream)
{
    const float* x  = (const float*)d_in[0];
    const float* rp = (const float*)d_in[1];
    GrapherP g1 = {(const float*)d_in[2],  (const float*)d_in[3],
                   (const float*)d_in[4],  (const float*)d_in[5],
                   (const float*)d_in[6],  (const float*)d_in[7]};
    GrapherP g2 = {(const float*)d_in[8],  (const float*)d_in[9],
                   (const float*)d_in[10], (const float*)d_in[11],
                   (const float*)d_in[12], (const float*)d_in[13]};
    const float* f1w1 = (const float*)d_in[14]; const float* f1b1 = (const float*)d_in[15];
    const float* f1w2 = (const float*)d_in[16]; const float* f1b2 = (const float*)d_in[17];
    const float* f2w1 = (const float*)d_in[18]; const float* f2b1 = (const float*)d_in[19];
    const float* f2w2 = (const float*)d_in[20]; const float* f2b2 = (const float*)d_in[21];
    float* out = (float*)d_out;

    const size_t P  = (size_t)BB * CC * NN;     // 2,408,448 floats
    const size_t P4 = 4 * P;
    float* ws   = (float*)d_ws;
    float* bufA = ws;                 // P4
    float* bufB = bufA + P4;          // P4
    float* xnb  = bufB + P4;          // P
    float* cur0 = xnb + P;            // P
    float* cur1 = cur0 + P;           // P
    float* sqc  = cur1 + P;           // B*N
    int*   idx  = (int*)(sqc + (size_t)BB * NN);   // B*N*9 ints

    run_grapher(x, rp, g1, cur0, bufA, bufB, xnb, sqc, idx, stream);
    run_ffn(cur0, f1w1, f1b1, f1w2, f1b2, cur1, bufA, bufB, stream);
    inorm(cur1, cur0, nullptr, CC, 2, stream);
    run_grapher(cur0, rp, g2, cur1, bufA, bufB, xnb, sqc, idx, stream);
    run_ffn(cur1, f2w1, f2b1, f2w2, f2b2, cur0, bufA, bufB, stream);
    inorm(cur0, out, x, CC, 0, stream);
    (void)in_sizes; (void)n_in; (void)out_size; (void)ws_size;
}

// Round 11
// 1159.645 us; speedup vs baseline: 1.3011x; 1.1355x over previous
//
#include <hip/hip_runtime.h>
#include <math.h>

#define NN 3136      // H*W = 56*56
#define CC 96
#define BB 8
#define KNB 9
#define PARTS 7      // 7 parts x 14 m-tiles x 32 = 3136 cols
#define FLT_MAX_ 3.402823466e+38f
typedef unsigned long long u64;
typedef unsigned short ushortT;
typedef __attribute__((ext_vector_type(8))) short short8;   // 8 bf16 (4 VGPR)
typedef __attribute__((ext_vector_type(4))) float f32x4;

// ---------------------------------------------------------------------------
// 1x1 conv as batched GEMM (baseline version, known-good)
// ---------------------------------------------------------------------------
__global__ __launch_bounds__(256) void conv1_kernel(
    const float* __restrict__ in, const float* __restrict__ w,
    const float* __restrict__ bias, float* __restrict__ out, int K, int O)
{
    __shared__ float sW[16][64];   // [kk][o]
    __shared__ float sX[16][64];   // [kk][n]
    const int b  = blockIdx.z;
    const int n0 = blockIdx.x * 64;
    const int o0 = blockIdx.y * 64;
    const int tid = threadIdx.x;
    const int tx = tid & 15, ty = tid >> 4;
    const float* inb = in + (size_t)b * K * NN;

    float acc[4][4] = {{0.f}};

    for (int kb = 0; kb < K; kb += 16) {
        __syncthreads();
        {
            int o  = tid >> 2;
            int k4 = (tid & 3) << 2;
            float4 wv = make_float4(0.f, 0.f, 0.f, 0.f);
            if (o0 + o < O)
                wv = *(const float4*)&w[(size_t)(o0 + o) * K + kb + k4];
            sW[k4 + 0][o] = wv.x; sW[k4 + 1][o] = wv.y;
            sW[k4 + 2][o] = wv.z; sW[k4 + 3][o] = wv.w;
        }
        #pragma unroll
        for (int i = 0; i < 4; i++) {
            int e = tid + i * 256;
            int kk = e >> 6, n2 = e & 63;
            sX[kk][n2] = inb[(size_t)(kb + kk) * NN + n0 + n2];
        }
        __syncthreads();
        #pragma unroll
        for (int kk = 0; kk < 16; kk++) {
            const float4 av = *(const float4*)&sW[kk][ty << 2];
            const float4 xv = *(const float4*)&sX[kk][tx << 2];
            float a_[4] = {av.x, av.y, av.z, av.w};
            float x_[4] = {xv.x, xv.y, xv.z, xv.w};
            #pragma unroll
            for (int i = 0; i < 4; i++)
                #pragma unroll
                for (int j = 0; j < 4; j++)
                    acc[i][j] = fmaf(a_[i], x_[j], acc[i][j]);
        }
    }
    #pragma unroll
    for (int i = 0; i < 4; i++) {
        int o = o0 + (ty << 2) + i;
        if (o < O) {
            float bo = bias[o];
            float4 v = make_float4(acc[i][0] + bo, acc[i][1] + bo,
                                   acc[i][2] + bo, acc[i][3] + bo);
            *(float4*)&out[((size_t)b * O + o) * NN + n0 + (tx << 2)] = v;
        }
    }
}

// ---------------------------------------------------------------------------
// Instance norm over N per (b,c) row; act: 0 none, 1 gelu, 2 relu
// ---------------------------------------------------------------------------
__global__ __launch_bounds__(256) void inorm_kernel(
    const float* __restrict__ in, float* __restrict__ out,
    const float* __restrict__ res, int act)
{
    const int row = blockIdx.x;
    const float* x = in + (size_t)row * NN;
    const int tid = threadIdx.x;

    float v[13];
    float s = 0.f;
    #pragma unroll
    for (int i = 0; i < 13; i++) {
        int idx = tid + i * 256;
        v[i] = (idx < NN) ? x[idx] : 0.f;
        s += v[i];
    }
    __shared__ float red[4];
    #pragma unroll
    for (int off = 32; off > 0; off >>= 1) s += __shfl_down(s, off);
    if ((tid & 63) == 0) red[tid >> 6] = s;
    __syncthreads();
    const float mean = (red[0] + red[1] + red[2] + red[3]) * (1.f / (float)NN);

    float s2 = 0.f;
    #pragma unroll
    for (int i = 0; i < 13; i++) {
        int idx = tid + i * 256;
        if (idx < NN) { float d = v[i] - mean; s2 = fmaf(d, d, s2); }
    }
    #pragma unroll
    for (int off = 32; off > 0; off >>= 1) s2 += __shfl_down(s2, off);
    __syncthreads();
    if ((tid & 63) == 0) red[tid >> 6] = s2;
    __syncthreads();
    const float var = (red[0] + red[1] + red[2] + red[3]) * (1.f / (float)NN);
    const float rs = rsqrtf(var + 1e-5f);

    float* o = out + (size_t)row * NN;
    const float* rr = res ? (res + (size_t)row * NN) : nullptr;
    #pragma unroll
    for (int i = 0; i < 13; i++) {
        int idx = tid + i * 256;
        if (idx < NN) {
            float y = (v[i] - mean) * rs;
            if (act == 1)      y = 0.5f * y * (1.f + erff(y * 0.70710678118654752f));
            else if (act == 2) y = fmaxf(y, 0.f);
            if (rr) y += rr[idx];
            o[idx] = y;
        }
    }
}

// ---------------------------------------------------------------------------
// bf16 round-to-nearest-even helper
// ---------------------------------------------------------------------------
__device__ __forceinline__ unsigned bf16rne(float x)
{
    unsigned u = __float_as_uint(x);
    return (u + 0x7fffu + ((u >> 16) & 1u)) >> 16;
}

// ---------------------------------------------------------------------------
// Column (channel) L2-normalize; emit 3-way bf16 split (h+m+l == xn to
// ~2^-25) in [b][n][c] layout + sq[b,n] = sum_c xn^2 (fp32).
// ---------------------------------------------------------------------------
__global__ __launch_bounds__(256) void colnorm_kernel(
    const float* __restrict__ xf, ushortT* __restrict__ xh,
    ushortT* __restrict__ xm, ushortT* __restrict__ xl,
    float* __restrict__ sqc)
{
    const int g = blockIdx.x * 256 + threadIdx.x;   // over B*N
    const int b = g / NN;
    const int n = g - b * NN;
    const float* p = xf + (size_t)b * CC * NN + n;

    float s = 0.f;
    for (int c = 0; c < CC; c++) { float t = p[(size_t)c * NN]; s = fmaf(t, t, s); }
    const float den = fmaxf(sqrtf(s), 1e-12f);

    const size_t o = (size_t)g * CC;
    float sq = 0.f;
    for (int c = 0; c < CC; c++) {
        float t = p[(size_t)c * NN] / den;
        sq = fmaf(t, t, sq);
        unsigned hr = bf16rne(t);
        float hf = __uint_as_float(hr << 16);
        float r1 = t - hf;
        unsigned mr = bf16rne(r1);
        float mf = __uint_as_float(mr << 16);
        float r2 = r1 - mf;
        unsigned lr = bf16rne(r2);
        xh[o + c] = (ushortT)hr;
        xm[o + c] = (ushortT)mr;
        xl[o + c] = (ushortT)lr;
    }
    sqc[g] = sq;
}

// ---------------------------------------------------------------------------
// u64-key top-9: key = (ord(dist) << 32) | m.  min-u64 == (min d, then min m)
// ---------------------------------------------------------------------------
__device__ __forceinline__ u64 dkey(float d, int m)
{
    unsigned int ub = __float_as_uint(d);
    ub ^= (unsigned int)(((int)ub) >> 31) | 0x80000000u;
    return ((u64)ub << 32) | (unsigned int)m;
}
__device__ __forceinline__ void ins9u(u64 (&kk)[9], u64 key)
{
    if (key < kk[8]) {
        kk[8] = key;
        #pragma unroll
        for (int j = 8; j > 0; --j) {
            if (kk[j] < kk[j - 1]) {
                u64 t = kk[j]; kk[j] = kk[j - 1]; kk[j - 1] = t;
            }
        }
    }
}

// ---------------------------------------------------------------------------
// Fused distance GEMM (MFMA, bf16 3-split) + top-9 select (v6).
// dot(r,m) via 6 mfma passes (hh,hm,mh,mm,hl,lh) over K=96 in 3 chunks of 32.
// Layout-risk cancellation: both operands staged from the same [n][c] data
// with the same assumed k-map -> any k-permutation misassumption cancels in
// the sum; C/D transpose cancels because dot is symmetric.
// Block: 64 rows x 14 m-tiles of 32 cols, 512 threads = 8 waves,
// wave w owns D-tile (row-tile w&3, col-tile w>>2). D via LDS roundtrip;
// selection = proven u64 insert (1 list/thread) + 8-lane tournament.
// grid: (NN/64, PARTS, BB), 512 threads.
// ---------------------------------------------------------------------------
__global__ __launch_bounds__(512, 4) void knn_mfma_kernel(
    const ushortT* __restrict__ xh, const ushortT* __restrict__ xm,
    const ushortT* __restrict__ xl, const float* __restrict__ sqc,
    const float* __restrict__ rp, u64* __restrict__ pko)
{
    __shared__ ushortT shA[3][64][104];   // [split][row][c], pad 96->104
    __shared__ ushortT shB[3][32][104];
    __shared__ float   shD[64][33];       // pad 32->33 (write-bank spread)
    const int b    = blockIdx.z;
    const int part = blockIdx.y;
    const int r0   = blockIdx.x * 64;
    const int tid  = threadIdx.x;
    const int ty = tid >> 3;             // 0..63 selection row
    const int tx = tid & 7;              // 0..7  col group (4 cols)
    const int w  = tid >> 6;             // wave 0..7
    const int l  = tid & 63;             // lane
    const int Rt = w & 3;                // row-tile
    const int Mt = w >> 2;               // col-tile
    const int fr = l & 15;               // fragment row/col
    const int fq = l >> 4;               // k-quad
    const float* sqb = sqc + (size_t)b * NN;

    // stage shA: 3 splits x 64 rows x 12 chunks-of-8 = 2304 float4 loads
    #pragma unroll
    for (int i = 0; i < 5; i++) {
        int idx = tid + i * 512;
        if (idx < 2304) {
            int s = idx / 768, rem = idx - s * 768;
            int r = rem / 12, cc = (rem - r * 12) * 8;
            const ushortT* bp = (s == 0) ? xh : ((s == 1) ? xm : xl);
            *(float4*)&shA[s][r][cc] =
                *(const float4*)&bp[((size_t)(b * NN + r0 + r)) * CC + cc];
        }
    }

    u64 kk0[9];
    #pragma unroll
    for (int j = 0; j < 9; j++) kk0[j] = 0xFFFFFFFFFFFFFFFFull;

    for (int mt = 0; mt < 14; mt++) {
        const int m0 = part * 448 + mt * 32;

        // stage shB: 3 x 32 x 12 = 1152 float4 loads (after prev epilogue --
        // prev mfma readers of shB finished before the prev bar2)
        #pragma unroll
        for (int i = 0; i < 3; i++) {
            int idx = tid + i * 512;
            if (idx < 1152) {
                int s = idx / 384, rem = idx - s * 384;
                int m = rem / 12, cc = (rem - m * 12) * 8;
                const ushortT* bp = (s == 0) ? xh : ((s == 1) ? xm : xl);
                *(float4*)&shB[s][m][cc] =
                    *(const float4*)&bp[((size_t)(b * NN + m0 + m)) * CC + cc];
            }
        }
        // rp/sq for epilogue: issued here, consumed after bar2 (hidden)
        const float4 sqv = *(const float4*)&sqb[m0 + tx * 4];
        const float4 rpv = *(const float4*)&rp[(size_t)(r0 + ty) * NN + m0 + tx * 4];
        __syncthreads();   // bar1: shA(first iter)/shB staged; prev shD reads done

        // MFMA: this wave's 16x16 D-tile, K=96 in 3 chunks, 6 split-passes
        f32x4 acc = {0.f, 0.f, 0.f, 0.f};
        #pragma unroll
        for (int kc = 0; kc < 3; kc++) {
            const int ca = kc * 32 + fq * 8;
            const short8 ah = *(const short8*)&shA[0][Rt * 16 + fr][ca];
            const short8 am = *(const short8*)&shA[1][Rt * 16 + fr][ca];
            const short8 al = *(const short8*)&shA[2][Rt * 16 + fr][ca];
            const short8 bh = *(const short8*)&shB[0][Mt * 16 + fr][ca];
            const short8 bm = *(const short8*)&shB[1][Mt * 16 + fr][ca];
            const short8 bl = *(const short8*)&shB[2][Mt * 16 + fr][ca];
            acc = __builtin_amdgcn_mfma_f32_16x16x32_bf16(ah, bh, acc, 0, 0, 0);
            acc = __builtin_amdgcn_mfma_f32_16x16x32_bf16(ah, bm, acc, 0, 0, 0);
            acc = __builtin_amdgcn_mfma_f32_16x16x32_bf16(am, bh, acc, 0, 0, 0);
            acc = __builtin_amdgcn_mfma_f32_16x16x32_bf16(am, bm, acc, 0, 0, 0);
            acc = __builtin_amdgcn_mfma_f32_16x16x32_bf16(ah, bl, acc, 0, 0, 0);
            acc = __builtin_amdgcn_mfma_f32_16x16x32_bf16(al, bh, acc, 0, 0, 0);
        }
        // C/D layout (m89): col = lane&15, row = (lane>>4)*4 + q
        #pragma unroll
        for (int q = 0; q < 4; q++)
            shD[Rt * 16 + fq * 4 + q][Mt * 16 + fr] = acc[q];
        __syncthreads();   // bar2: shD complete

        // epilogue: dist -> u64 keys -> per-thread top-9 (1 row x 4 cols)
        const float d0 = shD[ty][tx * 4 + 0];
        const float d1 = shD[ty][tx * 4 + 1];
        const float d2 = shD[ty][tx * 4 + 2];
        const float d3 = shD[ty][tx * 4 + 3];
        const int mb = m0 + tx * 4;
        ins9u(kk0, dkey(fmaf(-2.f, d0, sqv.x + rpv.x), mb + 0));
        ins9u(kk0, dkey(fmaf(-2.f, d1, sqv.y + rpv.y), mb + 1));
        ins9u(kk0, dkey(fmaf(-2.f, d2, sqv.z + rpv.z), mb + 2));
        ins9u(kk0, dkey(fmaf(-2.f, d3, sqv.w + rpv.w), mb + 3));
    }

    // tournament merge across the aligned 8-lane row-group (tx 0..7)
    const size_t base = ((size_t)(b * NN + r0 + ty) * PARTS + part) * KNB;
    #pragma unroll
    for (int k = 0; k < 9; k++) {
        u64 wv = kk0[0];
        #pragma unroll
        for (int off = 1; off < 8; off <<= 1) {
            unsigned int lo = __shfl_xor((unsigned int)wv, off);
            unsigned int hi = __shfl_xor((unsigned int)(wv >> 32), off);
            u64 o = ((u64)hi << 32) | lo;
            wv = (o < wv) ? o : wv;
        }
        if (kk0[0] == wv) {            // unique winner (keys contain m)
            #pragma unroll
            for (int j = 0; j < 8; j++) kk0[j] = kk0[j + 1];
            kk0[8] = 0xFFFFFFFFFFFFFFFFull;
        }
        if (tx == 0) pko[base + k] = wv;
    }
}

// ---------------------------------------------------------------------------
// Merge PARTS sorted 9-lists (u64 keys) per (b,n) -> final nn_idx
// ---------------------------------------------------------------------------
__global__ __launch_bounds__(256) void knn_merge_kernel(
    const u64* __restrict__ pko, int* __restrict__ nn_idx)
{
    const int g = blockIdx.x * 256 + threadIdx.x;   // over B*N
    if (g >= BB * NN) return;
    u64 kk[9];
    #pragma unroll
    for (int j = 0; j < 9; j++) kk[j] = 0xFFFFFFFFFFFFFFFFull;
    const u64* v = pko + (size_t)g * PARTS * KNB;
    for (int p = 0; p < PARTS; p++)
        #pragma unroll
        for (int j = 0; j < 9; j++)
            ins9u(kk, v[p * KNB + j]);
    #pragma unroll
    for (int j = 0; j < 9; j++)
        nn_idx[(size_t)g * KNB + j] = (int)(kk[j] & 0xFFFFFFFFu);
}

// ---------------------------------------------------------------------------
// Max-relative gather + channel interleave
// ---------------------------------------------------------------------------
__global__ __launch_bounds__(256) void gather_kernel(
    const float* __restrict__ xf, const int* __restrict__ nn_idx,
    float* __restrict__ y)
{
    const size_t g = (size_t)blockIdx.x * 256 + threadIdx.x;   // over B*C*N
    const int n  = (int)(g % NN);
    const int bc = (int)(g / NN);
    const int c  = bc % CC;
    const int b  = bc / CC;
    const float* row = xf + (size_t)(b * CC + c) * NN;
    const float xi = row[n];
    const int* id = nn_idx + ((size_t)b * NN + n) * KNB;
    float mx = -FLT_MAX_;
    #pragma unroll
    for (int k = 0; k < KNB; k++) mx = fmaxf(mx, row[id[k]] - xi);
    float* o = y + ((size_t)b * 2 * CC + 2 * c) * NN + n;
    o[0]  = xi;
    o[NN] = mx;
}

// ---------------------------------------------------------------------------
// Host-side orchestration
// ---------------------------------------------------------------------------
static void conv1(const float* in, const float* w, const float* b, float* out,
                  int K, int O, hipStream_t s)
{
    dim3 grid(NN / 64, (O + 63) / 64, BB);
    conv1_kernel<<<grid, 256, 0, s>>>(in, w, b, out, K, O);
}
static void inorm(const float* in, float* out, const float* res, int ch, int act,
                  hipStream_t s)
{
    inorm_kernel<<<BB * ch, 256, 0, s>>>(in, out, res, act);
}

struct GrapherP {
    const float *fc1w, *fc1b, *mrw, *mrb, *fc2w, *fc2b;
};

static void run_grapher(const float* in, const float* rp, const GrapherP& p,
                        float* outCur, float* bufA, float* bufB,
                        ushortT* xh, ushortT* xm, ushortT* xl,
                        float* sqc, int* idx, hipStream_t s)
{
    conv1(in, p.fc1w, p.fc1b, bufA, CC, CC, s);
    inorm(bufA, bufB, nullptr, CC, 0, s);                         // xf
    colnorm_kernel<<<(BB * NN) / 256, 256, 0, s>>>(bufB, xh, xm, xl, sqc);
    // partial-key scratch lives in bufA (free until gather writes it)
    u64* pko = (u64*)bufA;
    knn_mfma_kernel<<<dim3(NN / 64, PARTS, BB), 512, 0, s>>>(
        xh, xm, xl, sqc, rp, pko);
    knn_merge_kernel<<<(BB * NN + 255) / 256, 256, 0, s>>>(pko, idx);
    gather_kernel<<<(BB * CC * NN) / 256, 256, 0, s>>>(bufB, idx, bufA);  // 2C
    conv1(bufA, p.mrw, p.mrb, bufB, 2 * CC, 2 * CC, s);
    inorm(bufB, bufA, nullptr, 2 * CC, 1, s);                     // gelu
    conv1(bufA, p.fc2w, p.fc2b, bufB, 2 * CC, CC, s);
    inorm(bufB, outCur, in, CC, 0, s);                            // + shortcut
}

static void run_ffn(const float* in, const float* w1, const float* b1,
                    const float* w2, const float* b2,
                    float* outCur, float* bufA, float* bufB, hipStream_t s)
{
    conv1(in, w1, b1, bufA, CC, 4 * CC, s);
    inorm(bufA, bufB, nullptr, 4 * CC, 1, s);                     // gelu
    conv1(bufB, w2, b2, bufA, 2 * CC * 2, CC, s);
    inorm(bufA, outCur, in, CC, 0, s);                            // + shortcut
}

extern "C" void kernel_launch(void* const* d_in, const int* in_sizes, int n_in,
                              void* d_out, int out_size, void* d_ws, size_t ws_size,
                              hipStream_t stream)
{
    const float* x  = (const float*)d_in[0];
    const float* rp = (const float*)d_in[1];
    GrapherP g1 = {(const float*)d_in[2],  (const float*)d_in[3],
                   (const float*)d_in[4],  (const float*)d_in[5],
                   (const float*)d_in[6],  (const float*)d_in[7]};
    GrapherP g2 = {(const float*)d_in[8],  (const float*)d_in[9],
                   (const float*)d_in[10], (const float*)d_in[11],
                   (const float*)d_in[12], (const float*)d_in[13]};
    const float* f1w1 = (const float*)d_in[14]; const float* f1b1 = (const float*)d_in[15];
    const float* f1w2 = (const float*)d_in[16]; const float* f1b2 = (const float*)d_in[17];
    const float* f2w1 = (const float*)d_in[18]; const float* f2b1 = (const float*)d_in[19];
    const float* f2w2 = (const float*)d_in[20]; const float* f2b2 = (const float*)d_in[21];
    float* out = (float*)d_out;

    const size_t P  = (size_t)BB * CC * NN;     // 2,408,448 elements
    const size_t P4 = 4 * P;
    float* ws   = (float*)d_ws;
    float* bufA = ws;                 // P4 floats
    float* bufB = bufA + P4;          // P4
    float* cur0 = bufB + P4;          // P
    float* cur1 = cur0 + P;           // P
    float* sqc  = cur1 + P;           // B*N
    int*   idx  = (int*)(sqc + (size_t)BB * NN);        // B*N*9 ints
    ushortT* xh = (ushortT*)(idx + (size_t)BB * NN * KNB);  // P ushorts
    ushortT* xm = xh + P;                                    // P ushorts
    ushortT* xl = xm + P;                                    // P ushorts

    run_grapher(x, rp, g1, cur0, bufA, bufB, xh, xm, xl, sqc, idx, stream);
    run_ffn(cur0, f1w1, f1b1, f1w2, f1b2, cur1, bufA, bufB, stream);
    inorm(cur1, cur0, nullptr, CC, 2, stream);
    run_grapher(cur0, rp, g2, cur1, bufA, bufB, xh, xm, xl, sqc, idx, stream);
    run_ffn(cur1, f2w1, f2b1, f2w2, f2b2, cur0, bufA, bufB, stream);
    inorm(cur0, out, x, CC, 0, stream);
    (void)in_sizes; (void)n_in; (void)out_size; (void)ws_size;
}

// Round 12
// 1098.983 us; speedup vs baseline: 1.3729x; 1.0552x over previous
//
#include <hip/hip_runtime.h>
#include <math.h>

#define NN 3136      // H*W = 56*56
#define CC 96
#define BB 8
#define KNB 9
#define PARTS 7      // 7 parts x 14 m-tiles x 32 = 3136 cols
#define FLT_MAX_ 3.402823466e+38f
typedef unsigned long long u64;
typedef unsigned short ushortT;
typedef __attribute__((ext_vector_type(8))) short short8;   // 8 bf16 (4 VGPR)
typedef __attribute__((ext_vector_type(4))) float f32x4;

// ---------------------------------------------------------------------------
// 1x1 conv as batched GEMM (baseline version, known-good)
// ---------------------------------------------------------------------------
__global__ __launch_bounds__(256) void conv1_kernel(
    const float* __restrict__ in, const float* __restrict__ w,
    const float* __restrict__ bias, float* __restrict__ out, int K, int O)
{
    __shared__ float sW[16][64];   // [kk][o]
    __shared__ float sX[16][64];   // [kk][n]
    const int b  = blockIdx.z;
    const int n0 = blockIdx.x * 64;
    const int o0 = blockIdx.y * 64;
    const int tid = threadIdx.x;
    const int tx = tid & 15, ty = tid >> 4;
    const float* inb = in + (size_t)b * K * NN;

    float acc[4][4] = {{0.f}};

    for (int kb = 0; kb < K; kb += 16) {
        __syncthreads();
        {
            int o  = tid >> 2;
            int k4 = (tid & 3) << 2;
            float4 wv = make_float4(0.f, 0.f, 0.f, 0.f);
            if (o0 + o < O)
                wv = *(const float4*)&w[(size_t)(o0 + o) * K + kb + k4];
            sW[k4 + 0][o] = wv.x; sW[k4 + 1][o] = wv.y;
            sW[k4 + 2][o] = wv.z; sW[k4 + 3][o] = wv.w;
        }
        #pragma unroll
        for (int i = 0; i < 4; i++) {
            int e = tid + i * 256;
            int kk = e >> 6, n2 = e & 63;
            sX[kk][n2] = inb[(size_t)(kb + kk) * NN + n0 + n2];
        }
        __syncthreads();
        #pragma unroll
        for (int kk = 0; kk < 16; kk++) {
            const float4 av = *(const float4*)&sW[kk][ty << 2];
            const float4 xv = *(const float4*)&sX[kk][tx << 2];
            float a_[4] = {av.x, av.y, av.z, av.w};
            float x_[4] = {xv.x, xv.y, xv.z, xv.w};
            #pragma unroll
            for (int i = 0; i < 4; i++)
                #pragma unroll
                for (int j = 0; j < 4; j++)
                    acc[i][j] = fmaf(a_[i], x_[j], acc[i][j]);
        }
    }
    #pragma unroll
    for (int i = 0; i < 4; i++) {
        int o = o0 + (ty << 2) + i;
        if (o < O) {
            float bo = bias[o];
            float4 v = make_float4(acc[i][0] + bo, acc[i][1] + bo,
                                   acc[i][2] + bo, acc[i][3] + bo);
            *(float4*)&out[((size_t)b * O + o) * NN + n0 + (tx << 2)] = v;
        }
    }
}

// ---------------------------------------------------------------------------
// Instance norm over N per (b,c) row; act: 0 none, 1 gelu, 2 relu
// ---------------------------------------------------------------------------
__global__ __launch_bounds__(256) void inorm_kernel(
    const float* __restrict__ in, float* __restrict__ out,
    const float* __restrict__ res, int act)
{
    const int row = blockIdx.x;
    const float* x = in + (size_t)row * NN;
    const int tid = threadIdx.x;

    float v[13];
    float s = 0.f;
    #pragma unroll
    for (int i = 0; i < 13; i++) {
        int idx = tid + i * 256;
        v[i] = (idx < NN) ? x[idx] : 0.f;
        s += v[i];
    }
    __shared__ float red[4];
    #pragma unroll
    for (int off = 32; off > 0; off >>= 1) s += __shfl_down(s, off);
    if ((tid & 63) == 0) red[tid >> 6] = s;
    __syncthreads();
    const float mean = (red[0] + red[1] + red[2] + red[3]) * (1.f / (float)NN);

    float s2 = 0.f;
    #pragma unroll
    for (int i = 0; i < 13; i++) {
        int idx = tid + i * 256;
        if (idx < NN) { float d = v[i] - mean; s2 = fmaf(d, d, s2); }
    }
    #pragma unroll
    for (int off = 32; off > 0; off >>= 1) s2 += __shfl_down(s2, off);
    __syncthreads();
    if ((tid & 63) == 0) red[tid >> 6] = s2;
    __syncthreads();
    const float var = (red[0] + red[1] + red[2] + red[3]) * (1.f / (float)NN);
    const float rs = rsqrtf(var + 1e-5f);

    float* o = out + (size_t)row * NN;
    const float* rr = res ? (res + (size_t)row * NN) : nullptr;
    #pragma unroll
    for (int i = 0; i < 13; i++) {
        int idx = tid + i * 256;
        if (idx < NN) {
            float y = (v[i] - mean) * rs;
            if (act == 1)      y = 0.5f * y * (1.f + erff(y * 0.70710678118654752f));
            else if (act == 2) y = fmaxf(y, 0.f);
            if (rr) y += rr[idx];
            o[idx] = y;
        }
    }
}

// ---------------------------------------------------------------------------
// bf16 round-to-nearest-even helper
// ---------------------------------------------------------------------------
__device__ __forceinline__ unsigned bf16rne(float x)
{
    unsigned u = __float_as_uint(x);
    return (u + 0x7fffu + ((u >> 16) & 1u)) >> 16;
}

// ---------------------------------------------------------------------------
// Column (channel) L2-normalize; emit 3-way bf16 split (h+m+l == xn to
// ~2^-25) in [b][n][c] layout + sq[b,n] = sum_c xn^2 (fp32).
// ---------------------------------------------------------------------------
__global__ __launch_bounds__(256) void colnorm_kernel(
    const float* __restrict__ xf, ushortT* __restrict__ xh,
    ushortT* __restrict__ xm, ushortT* __restrict__ xl,
    float* __restrict__ sqc)
{
    const int g = blockIdx.x * 256 + threadIdx.x;   // over B*N
    const int b = g / NN;
    const int n = g - b * NN;
    const float* p = xf + (size_t)b * CC * NN + n;

    float s = 0.f;
    for (int c = 0; c < CC; c++) { float t = p[(size_t)c * NN]; s = fmaf(t, t, s); }
    const float den = fmaxf(sqrtf(s), 1e-12f);

    const size_t o = (size_t)g * CC;
    float sq = 0.f;
    for (int c = 0; c < CC; c++) {
        float t = p[(size_t)c * NN] / den;
        sq = fmaf(t, t, sq);
        unsigned hr = bf16rne(t);
        float hf = __uint_as_float(hr << 16);
        float r1 = t - hf;
        unsigned mr = bf16rne(r1);
        float mf = __uint_as_float(mr << 16);
        float r2 = r1 - mf;
        unsigned lr = bf16rne(r2);
        xh[o + c] = (ushortT)hr;
        xm[o + c] = (ushortT)mr;
        xl[o + c] = (ushortT)lr;
    }
    sqc[g] = sq;
}

// ---------------------------------------------------------------------------
// u64-key top-9: key = (ord(dist) << 32) | m.  min-u64 == (min d, then min m)
// ---------------------------------------------------------------------------
__device__ __forceinline__ u64 dkey(float d, int m)
{
    unsigned int ub = __float_as_uint(d);
    ub ^= (unsigned int)(((int)ub) >> 31) | 0x80000000u;
    return ((u64)ub << 32) | (unsigned int)m;
}
__device__ __forceinline__ void ins9u(u64 (&kk)[9], u64 key)
{
    if (key < kk[8]) {
        kk[8] = key;
        #pragma unroll
        for (int j = 8; j > 0; --j) {
            if (kk[j] < kk[j - 1]) {
                u64 t = kk[j]; kk[j] = kk[j - 1]; kk[j - 1] = t;
            }
        }
    }
}

// ---------------------------------------------------------------------------
// Fused distance GEMM (MFMA, bf16 3-split) + top-9 select (v7).
// v6 reloaded the mt-invariant A-fragments from LDS every m-tile: 18 b128
// frag reads/mt made the LDS pipe the critical resource (~45% busy, 26.7M
// conflict cycles). v7: A-fragments loaded ONCE per block directly from
// global (L2/L3-resident, 16B-aligned) into 9 named short8 regs; shA LDS
// eliminated (68.6 -> 28.4 KB). Per-mt LDS frag traffic halves.
// Block: 64 rows x 14 m-tiles of 32 cols, 512 threads = 8 waves,
// wave w owns D-tile (row-tile w&3, col-tile w>>2). D via LDS roundtrip;
// selection = proven u64 insert (1 list/thread) + 8-lane tournament.
// grid: (NN/64, PARTS, BB), 512 threads.
// ---------------------------------------------------------------------------
__global__ __launch_bounds__(512, 4) void knn_mfma_kernel(
    const ushortT* __restrict__ xh, const ushortT* __restrict__ xm,
    const ushortT* __restrict__ xl, const float* __restrict__ sqc,
    const float* __restrict__ rp, u64* __restrict__ pko)
{
    __shared__ ushortT shB[3][32][104];   // [split][m][c], pad 96->104 (20KB)
    __shared__ float   shD[64][33];       // pad 32->33 (8.4KB)
    const int b    = blockIdx.z;
    const int part = blockIdx.y;
    const int r0   = blockIdx.x * 64;
    const int tid  = threadIdx.x;
    const int ty = tid >> 3;             // 0..63 selection row
    const int tx = tid & 7;              // 0..7  col group (4 cols)
    const int w  = tid >> 6;             // wave 0..7
    const int l  = tid & 63;             // lane
    const int Rt = w & 3;                // row-tile
    const int Mt = w >> 2;               // col-tile
    const int fr = l & 15;               // fragment row/col
    const int fq = l >> 4;               // k-quad
    const float* sqb = sqc + (size_t)b * NN;

    // A-fragments: once per block, straight from global (16B-aligned).
    // Lane supplies A[row = Rt*16+fr][k = kc*32 + fq*8 + e] -- identical
    // data the v6 shA reads produced.
    const size_t arow = ((size_t)(b * NN + r0 + Rt * 16 + fr)) * CC;
    const int ko = fq * 8;
    const short8 ah0 = *(const short8*)&xh[arow + ko];
    const short8 ah1 = *(const short8*)&xh[arow + 32 + ko];
    const short8 ah2 = *(const short8*)&xh[arow + 64 + ko];
    const short8 am0 = *(const short8*)&xm[arow + ko];
    const short8 am1 = *(const short8*)&xm[arow + 32 + ko];
    const short8 am2 = *(const short8*)&xm[arow + 64 + ko];
    const short8 al0 = *(const short8*)&xl[arow + ko];
    const short8 al1 = *(const short8*)&xl[arow + 32 + ko];
    const short8 al2 = *(const short8*)&xl[arow + 64 + ko];

    u64 kk0[9];
    #pragma unroll
    for (int j = 0; j < 9; j++) kk0[j] = 0xFFFFFFFFFFFFFFFFull;

    // prologue: stage shB for mt=0
    {
        const int m0 = part * 448;
        #pragma unroll
        for (int i = 0; i < 3; i++) {
            int idx = tid + i * 512;
            if (idx < 1152) {
                int s = idx / 384, rem = idx - s * 384;
                int m = rem / 12, cc = (rem - m * 12) * 8;
                const ushortT* bp = (s == 0) ? xh : ((s == 1) ? xm : xl);
                *(float4*)&shB[s][m][cc] =
                    *(const float4*)&bp[((size_t)(b * NN + m0 + m)) * CC + cc];
            }
        }
    }

    for (int mt = 0; mt < 14; mt++) {
        const int m0 = part * 448 + mt * 32;

        // rp/sq for epilogue: issued early, consumed at iteration end
        const float4 sqv = *(const float4*)&sqb[m0 + tx * 4];
        const float4 rpv = *(const float4*)&rp[(size_t)(r0 + ty) * NN + m0 + tx * 4];
        __syncthreads();   // bar1: shB(mt) staged; prev shD reads done

        // MFMA: this wave's 16x16 D-tile, K=96 in 3 chunks, 6 split-passes
        f32x4 acc = {0.f, 0.f, 0.f, 0.f};
        {
            const int ca = fq * 8;
            const short8 bh = *(const short8*)&shB[0][Mt * 16 + fr][ca];
            const short8 bm = *(const short8*)&shB[1][Mt * 16 + fr][ca];
            const short8 bl = *(const short8*)&shB[2][Mt * 16 + fr][ca];
            acc = __builtin_amdgcn_mfma_f32_16x16x32_bf16(ah0, bh, acc, 0, 0, 0);
            acc = __builtin_amdgcn_mfma_f32_16x16x32_bf16(ah0, bm, acc, 0, 0, 0);
            acc = __builtin_amdgcn_mfma_f32_16x16x32_bf16(am0, bh, acc, 0, 0, 0);
            acc = __builtin_amdgcn_mfma_f32_16x16x32_bf16(am0, bm, acc, 0, 0, 0);
            acc = __builtin_amdgcn_mfma_f32_16x16x32_bf16(ah0, bl, acc, 0, 0, 0);
            acc = __builtin_amdgcn_mfma_f32_16x16x32_bf16(al0, bh, acc, 0, 0, 0);
        }
        {
            const int ca = 32 + fq * 8;
            const short8 bh = *(const short8*)&shB[0][Mt * 16 + fr][ca];
            const short8 bm = *(const short8*)&shB[1][Mt * 16 + fr][ca];
            const short8 bl = *(const short8*)&shB[2][Mt * 16 + fr][ca];
            acc = __builtin_amdgcn_mfma_f32_16x16x32_bf16(ah1, bh, acc, 0, 0, 0);
            acc = __builtin_amdgcn_mfma_f32_16x16x32_bf16(ah1, bm, acc, 0, 0, 0);
            acc = __builtin_amdgcn_mfma_f32_16x16x32_bf16(am1, bh, acc, 0, 0, 0);
            acc = __builtin_amdgcn_mfma_f32_16x16x32_bf16(am1, bm, acc, 0, 0, 0);
            acc = __builtin_amdgcn_mfma_f32_16x16x32_bf16(ah1, bl, acc, 0, 0, 0);
            acc = __builtin_amdgcn_mfma_f32_16x16x32_bf16(al1, bh, acc, 0, 0, 0);
        }
        {
            const int ca = 64 + fq * 8;
            const short8 bh = *(const short8*)&shB[0][Mt * 16 + fr][ca];
            const short8 bm = *(const short8*)&shB[1][Mt * 16 + fr][ca];
            const short8 bl = *(const short8*)&shB[2][Mt * 16 + fr][ca];
            acc = __builtin_amdgcn_mfma_f32_16x16x32_bf16(ah2, bh, acc, 0, 0, 0);
            acc = __builtin_amdgcn_mfma_f32_16x16x32_bf16(ah2, bm, acc, 0, 0, 0);
            acc = __builtin_amdgcn_mfma_f32_16x16x32_bf16(am2, bh, acc, 0, 0, 0);
            acc = __builtin_amdgcn_mfma_f32_16x16x32_bf16(am2, bm, acc, 0, 0, 0);
            acc = __builtin_amdgcn_mfma_f32_16x16x32_bf16(ah2, bl, acc, 0, 0, 0);
            acc = __builtin_amdgcn_mfma_f32_16x16x32_bf16(al2, bh, acc, 0, 0, 0);
        }
        // C/D layout (m89): col = lane&15, row = (lane>>4)*4 + q
        #pragma unroll
        for (int q = 0; q < 4; q++)
            shD[Rt * 16 + fq * 4 + q][Mt * 16 + fr] = acc[q];
        __syncthreads();   // bar2: shD complete; all B-frag reads of mt done

        // stage shB for mt+1 (overwrites shB -- safe after bar2)
        if (mt + 1 < 14) {
            const int m0n = m0 + 32;
            #pragma unroll
            for (int i = 0; i < 3; i++) {
                int idx = tid + i * 512;
                if (idx < 1152) {
                    int s = idx / 384, rem = idx - s * 384;
                    int m = rem / 12, cc = (rem - m * 12) * 8;
                    const ushortT* bp = (s == 0) ? xh : ((s == 1) ? xm : xl);
                    *(float4*)&shB[s][m][cc] =
                        *(const float4*)&bp[((size_t)(b * NN + m0n + m)) * CC + cc];
                }
            }
        }

        // epilogue: dist -> u64 keys -> per-thread top-9 (1 row x 4 cols).
        // shD(mt) reads precede bar1(mt+1), so next shD writes can't race.
        const float d0 = shD[ty][tx * 4 + 0];
        const float d1 = shD[ty][tx * 4 + 1];
        const float d2 = shD[ty][tx * 4 + 2];
        const float d3 = shD[ty][tx * 4 + 3];
        const int mb = m0 + tx * 4;
        ins9u(kk0, dkey(fmaf(-2.f, d0, sqv.x + rpv.x), mb + 0));
        ins9u(kk0, dkey(fmaf(-2.f, d1, sqv.y + rpv.y), mb + 1));
        ins9u(kk0, dkey(fmaf(-2.f, d2, sqv.z + rpv.z), mb + 2));
        ins9u(kk0, dkey(fmaf(-2.f, d3, sqv.w + rpv.w), mb + 3));
    }

    // tournament merge across the aligned 8-lane row-group (tx 0..7)
    const size_t base = ((size_t)(b * NN + r0 + ty) * PARTS + part) * KNB;
    #pragma unroll
    for (int k = 0; k < 9; k++) {
        u64 wv = kk0[0];
        #pragma unroll
        for (int off = 1; off < 8; off <<= 1) {
            unsigned int lo = __shfl_xor((unsigned int)wv, off);
            unsigned int hi = __shfl_xor((unsigned int)(wv >> 32), off);
            u64 o = ((u64)hi << 32) | lo;
            wv = (o < wv) ? o : wv;
        }
        if (kk0[0] == wv) {            // unique winner (keys contain m)
            #pragma unroll
            for (int j = 0; j < 8; j++) kk0[j] = kk0[j + 1];
            kk0[8] = 0xFFFFFFFFFFFFFFFFull;
        }
        if (tx == 0) pko[base + k] = wv;
    }
}

// ---------------------------------------------------------------------------
// Merge PARTS sorted 9-lists (u64 keys) per (b,n) -> final nn_idx
// ---------------------------------------------------------------------------
__global__ __launch_bounds__(256) void knn_merge_kernel(
    const u64* __restrict__ pko, int* __restrict__ nn_idx)
{
    const int g = blockIdx.x * 256 + threadIdx.x;   // over B*N
    if (g >= BB * NN) return;
    u64 kk[9];
    #pragma unroll
    for (int j = 0; j < 9; j++) kk[j] = 0xFFFFFFFFFFFFFFFFull;
    const u64* v = pko + (size_t)g * PARTS * KNB;
    for (int p = 0; p < PARTS; p++)
        #pragma unroll
        for (int j = 0; j < 9; j++)
            ins9u(kk, v[p * KNB + j]);
    #pragma unroll
    for (int j = 0; j < 9; j++)
        nn_idx[(size_t)g * KNB + j] = (int)(kk[j] & 0xFFFFFFFFu);
}

// ---------------------------------------------------------------------------
// Max-relative gather + channel interleave
// ---------------------------------------------------------------------------
__global__ __launch_bounds__(256) void gather_kernel(
    const float* __restrict__ xf, const int* __restrict__ nn_idx,
    float* __restrict__ y)
{
    const size_t g = (size_t)blockIdx.x * 256 + threadIdx.x;   // over B*C*N
    const int n  = (int)(g % NN);
    const int bc = (int)(g / NN);
    const int c  = bc % CC;
    const int b  = bc / CC;
    const float* row = xf + (size_t)(b * CC + c) * NN;
    const float xi = row[n];
    const int* id = nn_idx + ((size_t)b * NN + n) * KNB;
    float mx = -FLT_MAX_;
    #pragma unroll
    for (int k = 0; k < KNB; k++) mx = fmaxf(mx, row[id[k]] - xi);
    float* o = y + ((size_t)b * 2 * CC + 2 * c) * NN + n;
    o[0]  = xi;
    o[NN] = mx;
}

// ---------------------------------------------------------------------------
// Host-side orchestration
// ---------------------------------------------------------------------------
static void conv1(const float* in, const float* w, const float* b, float* out,
                  int K, int O, hipStream_t s)
{
    dim3 grid(NN / 64, (O + 63) / 64, BB);
    conv1_kernel<<<grid, 256, 0, s>>>(in, w, b, out, K, O);
}
static void inorm(const float* in, float* out, const float* res, int ch, int act,
                  hipStream_t s)
{
    inorm_kernel<<<BB * ch, 256, 0, s>>>(in, out, res, act);
}

struct GrapherP {
    const float *fc1w, *fc1b, *mrw, *mrb, *fc2w, *fc2b;
};

static void run_grapher(const float* in, const float* rp, const GrapherP& p,
                        float* outCur, float* bufA, float* bufB,
                        ushortT* xh, ushortT* xm, ushortT* xl,
                        float* sqc, int* idx, hipStream_t s)
{
    conv1(in, p.fc1w, p.fc1b, bufA, CC, CC, s);
    inorm(bufA, bufB, nullptr, CC, 0, s);                         // xf
    colnorm_kernel<<<(BB * NN) / 256, 256, 0, s>>>(bufB, xh, xm, xl, sqc);
    // partial-key scratch lives in bufA (free until gather writes it)
    u64* pko = (u64*)bufA;
    knn_mfma_kernel<<<dim3(NN / 64, PARTS, BB), 512, 0, s>>>(
        xh, xm, xl, sqc, rp, pko);
    knn_merge_kernel<<<(BB * NN + 255) / 256, 256, 0, s>>>(pko, idx);
    gather_kernel<<<(BB * CC * NN) / 256, 256, 0, s>>>(bufB, idx, bufA);  // 2C
    conv1(bufA, p.mrw, p.mrb, bufB, 2 * CC, 2 * CC, s);
    inorm(bufB, bufA, nullptr, 2 * CC, 1, s);                     // gelu
    conv1(bufA, p.fc2w, p.fc2b, bufB, 2 * CC, CC, s);
    inorm(bufB, outCur, in, CC, 0, s);                            // + shortcut
}

static void run_ffn(const float* in, const float* w1, const float* b1,
                    const float* w2, const float* b2,
                    float* outCur, float* bufA, float* bufB, hipStream_t s)
{
    conv1(in, w1, b1, bufA, CC, 4 * CC, s);
    inorm(bufA, bufB, nullptr, 4 * CC, 1, s);                     // gelu
    conv1(bufB, w2, b2, bufA, 2 * CC * 2, CC, s);
    inorm(bufA, outCur, in, CC, 0, s);                            // + shortcut
}

extern "C" void kernel_launch(void* const* d_in, const int* in_sizes, int n_in,
                              void* d_out, int out_size, void* d_ws, size_t ws_size,
                              hipStream_t stream)
{
    const float* x  = (const float*)d_in[0];
    const float* rp = (const float*)d_in[1];
    GrapherP g1 = {(const float*)d_in[2],  (const float*)d_in[3],
                   (const float*)d_in[4],  (const float*)d_in[5],
                   (const float*)d_in[6],  (const float*)d_in[7]};
    GrapherP g2 = {(const float*)d_in[8],  (const float*)d_in[9],
                   (const float*)d_in[10], (const float*)d_in[11],
                   (const float*)d_in[12], (const float*)d_in[13]};
    const float* f1w1 = (const float*)d_in[14]; const float* f1b1 = (const float*)d_in[15];
    const float* f1w2 = (const float*)d_in[16]; const float* f1b2 = (const float*)d_in[17];
    const float* f2w1 = (const float*)d_in[18]; const float* f2b1 = (const float*)d_in[19];
    const float* f2w2 = (const float*)d_in[20]; const float* f2b2 = (const float*)d_in[21];
    float* out = (float*)d_out;

    const size_t P  = (size_t)BB * CC * NN;     // 2,408,448 elements
    const size_t P4 = 4 * P;
    float* ws   = (float*)d_ws;
    float* bufA = ws;                 // P4 floats
    float* bufB = bufA + P4;          // P4
    float* cur0 = bufB + P4;          // P
    float* cur1 = cur0 + P;           // P
    float* sqc  = cur1 + P;           // B*N
    int*   idx  = (int*)(sqc + (size_t)BB * NN);        // B*N*9 ints
    ushortT* xh = (ushortT*)(idx + (size_t)BB * NN * KNB);  // P ushorts
    ushortT* xm = xh + P;                                    // P ushorts
    ushortT* xl = xm + P;                                    // P ushorts

    run_grapher(x, rp, g1, cur0, bufA, bufB, xh, xm, xl, sqc, idx, stream);
    run_ffn(cur0, f1w1, f1b1, f1w2, f1b2, cur1, bufA, bufB, stream);
    inorm(cur1, cur0, nullptr, CC, 2, stream);
    run_grapher(cur0, rp, g2, cur1, bufA, bufB, xh, xm, xl, sqc, idx, stream);
    run_ffn(cur1, f2w1, f2b1, f2w2, f2b2, cur0, bufA, bufB, stream);
    inorm(cur0, out, x, CC, 0, stream);
    (void)in_sizes; (void)n_in; (void)out_size; (void)ws_size;
}